// Round 3
// baseline (297.330 us; speedup 1.0000x reference)
//
#include <hip/hip_runtime.h>
#include <math.h>

// B=1, C=64, H=W=64, N=4096, heads=8, dh=8, inner=64, hid_lc=32, hid_f=256.
#define NPIX 4096
#define IMG 64

typedef __attribute__((ext_vector_type(8))) short bf16x8;
typedef __attribute__((ext_vector_type(4))) float floatx4;
typedef __attribute__((ext_vector_type(4))) unsigned int uintx4;

// ---------------------------------------------------------------------------
// lc1 + luma pooling fused.
__global__ __launch_bounds__(256) void lc1_kernel(
    const float* __restrict__ luma, const float* __restrict__ w,
    const float* __restrict__ b, float* __restrict__ h1,
    float* __restrict__ pooled, float* __restrict__ sum) {
  __shared__ float red[256];
  int tid = threadIdx.x;
  int p = blockIdx.x * 256 + tid;
  int py = p >> 6, px = p & 63;
  float v[9];
#pragma unroll
  for (int dy = 0; dy < 3; dy++)
#pragma unroll
    for (int dx = 0; dx < 3; dx++) {
      int y = py + dy - 1, x = px + dx - 1;
      v[dy * 3 + dx] =
          (y >= 0 && y < IMG && x >= 0 && x < IMG) ? luma[y * IMG + x] : 0.f;
    }
  for (int oc = 0; oc < 32; oc++) {
    float s = b[oc];
#pragma unroll
    for (int t = 0; t < 9; t++) s = fmaf(w[oc * 9 + t], v[t], s);
    h1[oc * NPIX + p] = fmaxf(s, 0.f);
  }
  float sv = 0.f;
#pragma unroll
  for (int t = 0; t < 9; t++) sv += v[t];
  float cy = 3.f - (py == 0 ? 1.f : 0.f) - (py == 63 ? 1.f : 0.f);
  float cx = 3.f - (px == 0 ? 1.f : 0.f) - (px == 63 ? 1.f : 0.f);
  float pv = (cy * cx - sv) * (1.f / 9.f);
  pooled[p] = pv;
  red[tid] = pv;
  __syncthreads();
  for (int st = 128; st > 0; st >>= 1) {
    if (tid < st) red[tid] += red[tid + st];
    __syncthreads();
  }
  if (tid == 0) atomicAdd(sum, red[0]);
}

// ---------------------------------------------------------------------------
// lc2: h2 = relu(conv3x3(h1)), 32->32 ch, pad=1.
__global__ __launch_bounds__(256) void lc2_kernel(
    const float* __restrict__ h1, const float* __restrict__ w,
    const float* __restrict__ b, float* __restrict__ h2) {
  __shared__ float tin[32][324];
  __shared__ float sw[4][32][9];
  int tile = blockIdx.x, ocg = blockIdx.y;
  int ty0 = (tile >> 2) * 16, tx0 = (tile & 3) * 16;
  for (int idx = threadIdx.x; idx < 32 * 324; idx += 256) {
    int ic = idx / 324, pos = idx % 324;
    int py = pos / 18, px = pos % 18;
    int gy = ty0 + py - 1, gx = tx0 + px - 1;
    tin[ic][pos] = (gy >= 0 && gy < IMG && gx >= 0 && gx < IMG)
                       ? h1[ic * NPIX + gy * IMG + gx]
                       : 0.f;
  }
  for (int idx = threadIdx.x; idx < 4 * 32 * 9; idx += 256) {
    int o = idx / 288, r = idx % 288;
    sw[o][r / 9][r % 9] = w[(ocg * 4 + o) * 288 + r];
  }
  __syncthreads();
  int ly = threadIdx.x >> 4, lx = threadIdx.x & 15;
  int p = (ty0 + ly) * IMG + tx0 + lx;
  float acc[4];
#pragma unroll
  for (int o = 0; o < 4; o++) acc[o] = b[ocg * 4 + o];
  for (int ic = 0; ic < 32; ic++) {
    float v[9];
#pragma unroll
    for (int dy = 0; dy < 3; dy++)
#pragma unroll
      for (int dx = 0; dx < 3; dx++)
        v[dy * 3 + dx] = tin[ic][(ly + dy) * 18 + lx + dx];
#pragma unroll
    for (int o = 0; o < 4; o++)
#pragma unroll
      for (int t = 0; t < 9; t++) acc[o] = fmaf(sw[o][ic][t], v[t], acc[o]);
  }
#pragma unroll
  for (int o = 0; o < 4; o++)
    h2[(ocg * 4 + o) * NPIX + p] = fmaxf(acc[o], 0.f);
}

// ---------------------------------------------------------------------------
// Fused per-pixel LayerNorm + 1x1 conv GEMM (unchanged from r2).
__global__ __launch_bounds__(256) void ln_gemm_kernel(
    const float* __restrict__ X, const float* __restrict__ lnw,
    const float* __restrict__ lnb, const float* __restrict__ W,
    const float* __restrict__ bias, float* __restrict__ C) {
  __shared__ float xs[64][64];
  __shared__ float wsh[64][64];
  __shared__ float psum[4][64];
  __shared__ float mu[64];
  __shared__ float rs[64];
  int n0 = blockIdx.x * 64, m0 = blockIdx.y * 64;
  int tid = threadIdx.x;
  int c = tid >> 2, pg = (tid & 3) * 16;
  {
    const float4* src = (const float4*)&X[c * NPIX + n0 + pg];
    float4* dst = (float4*)&xs[c][pg];
    dst[0] = src[0]; dst[1] = src[1]; dst[2] = src[2]; dst[3] = src[3];
  }
  {
    int m = tid >> 2, kg = (tid & 3) * 16;
    const float4* wr = (const float4*)&W[(m0 + m) * 64 + kg];
    float4 w0 = wr[0], w1 = wr[1], w2 = wr[2], w3 = wr[3];
    float wv[16] = {w0.x, w0.y, w0.z, w0.w, w1.x, w1.y, w1.z, w1.w,
                    w2.x, w2.y, w2.z, w2.w, w3.x, w3.y, w3.z, w3.w};
#pragma unroll
    for (int j = 0; j < 16; j++) wsh[kg + j][m] = wv[j];
  }
  __syncthreads();
  int px = tid & 63, qq = tid >> 6;
  float s = 0.f;
#pragma unroll
  for (int cc = 0; cc < 16; cc++) s += xs[qq * 16 + cc][px];
  psum[qq][px] = s;
  __syncthreads();
  if (tid < 64) {
    float t = psum[0][tid] + psum[1][tid] + psum[2][tid] + psum[3][tid];
    mu[tid] = t * (1.f / 64.f);
  }
  __syncthreads();
  float mm = mu[px];
  s = 0.f;
#pragma unroll
  for (int cc = 0; cc < 16; cc++) {
    float d = xs[qq * 16 + cc][px] - mm;
    s = fmaf(d, d, s);
  }
  psum[qq][px] = s;
  __syncthreads();
  if (tid < 64) {
    float t = psum[0][tid] + psum[1][tid] + psum[2][tid] + psum[3][tid];
    rs[tid] = rsqrtf(t * (1.f / 64.f) + 1e-5f);
  }
  __syncthreads();
  {
    float wc = lnw[c], bc = lnb[c];
#pragma unroll
    for (int j = 0; j < 16; j++) {
      int p = pg + j;
      xs[c][p] = (xs[c][p] - mu[p]) * rs[p] * wc + bc;
    }
  }
  __syncthreads();
  int tx = tid & 15, ty = tid >> 4;
  float acc[4][4] = {};
#pragma unroll 8
  for (int kk = 0; kk < 64; kk++) {
    float4 a = *(const float4*)&wsh[kk][ty * 4];
    float4 b4 = *(const float4*)&xs[kk][tx * 4];
    float av[4] = {a.x, a.y, a.z, a.w};
    float bv[4] = {b4.x, b4.y, b4.z, b4.w};
#pragma unroll
    for (int im = 0; im < 4; im++)
#pragma unroll
      for (int in = 0; in < 4; in++)
        acc[im][in] = fmaf(av[im], bv[in], acc[im][in]);
  }
#pragma unroll
  for (int im = 0; im < 4; im++) {
    int m = m0 + ty * 4 + im;
    float bv = bias[m];
    float4 o = make_float4(acc[im][0] + bv, acc[im][1] + bv, acc[im][2] + bv,
                           acc[im][3] + bv);
    *(float4*)&C[m * NPIX + n0 + tx * 4] = o;
  }
}

// ---------------------------------------------------------------------------
// Thin GEMM (unchanged from r2): C[M][4096] = W[M][K]*X + bias (+resid).
__global__ __launch_bounds__(256) void gemm16_kernel(
    const float* __restrict__ W, const float* __restrict__ X,
    const float* __restrict__ bias, const float* __restrict__ resid,
    float* __restrict__ C, int K) {
  __shared__ float xs[32][64];
  __shared__ float wsh[32][16];
  int n0 = blockIdx.x * 64, m0 = blockIdx.y * 16;
  int tid = threadIdx.x;
  int m = tid >> 4, ng = tid & 15;
  float acc[4] = {};
  for (int k0 = 0; k0 < K; k0 += 32) {
    {
      int i0 = tid * 2;
      int k = i0 >> 4, nf = (i0 & 15) * 4;
      *(float4*)&xs[k][nf] = *(const float4*)&X[(k0 + k) * NPIX + n0 + nf];
      int i1 = i0 + 1;
      int k1 = i1 >> 4, nf1 = (i1 & 15) * 4;
      *(float4*)&xs[k1][nf1] = *(const float4*)&X[(k0 + k1) * NPIX + n0 + nf1];
    }
#pragma unroll
    for (int e = tid; e < 512; e += 256) {
      int mm = e >> 5, kk = e & 31;
      wsh[kk][mm] = W[(m0 + mm) * K + k0 + kk];
    }
    __syncthreads();
#pragma unroll 8
    for (int kk = 0; kk < 32; kk++) {
      float a = wsh[kk][m];
      float4 b4 = *(const float4*)&xs[kk][ng * 4];
      acc[0] = fmaf(a, b4.x, acc[0]);
      acc[1] = fmaf(a, b4.y, acc[1]);
      acc[2] = fmaf(a, b4.z, acc[2]);
      acc[3] = fmaf(a, b4.w, acc[3]);
    }
    __syncthreads();
  }
  int row = m0 + m;
  float bv = bias[row];
  float4 o = make_float4(acc[0] + bv, acc[1] + bv, acc[2] + bv, acc[3] + bv);
  if (resid) {
    const float4 r4 = *(const float4*)&resid[row * NPIX + n0 + ng * 4];
    o.x += r4.x; o.y += r4.y; o.z += r4.z; o.w += r4.w;
  }
  *(float4*)&C[row * NPIX + n0 + ng * 4] = o;
}

// ---------------------------------------------------------------------------
// gam+bet in one launch: blockIdx.y<4 -> gam, else bet. K=32 (single k-iter).
__global__ __launch_bounds__(256) void gemm_gb_kernel(
    const float* __restrict__ Wg, const float* __restrict__ Wb,
    const float* __restrict__ X, const float* __restrict__ bg,
    const float* __restrict__ bb, float* __restrict__ Cg,
    float* __restrict__ Cb) {
  __shared__ float xs[32][64];
  __shared__ float wsh[32][16];
  int yy = blockIdx.y;
  const float* W = yy < 4 ? Wg : Wb;
  const float* bias = yy < 4 ? bg : bb;
  float* C = yy < 4 ? Cg : Cb;
  int n0 = blockIdx.x * 64, m0 = (yy & 3) * 16;
  int tid = threadIdx.x;
  int m = tid >> 4, ng = tid & 15;
  float acc[4] = {};
  {
    int i0 = tid * 2;
    int k = i0 >> 4, nf = (i0 & 15) * 4;
    *(float4*)&xs[k][nf] = *(const float4*)&X[k * NPIX + n0 + nf];
    int i1 = i0 + 1;
    int k1 = i1 >> 4, nf1 = (i1 & 15) * 4;
    *(float4*)&xs[k1][nf1] = *(const float4*)&X[k1 * NPIX + n0 + nf1];
  }
#pragma unroll
  for (int e = tid; e < 512; e += 256) {
    int mm = e >> 5, kk = e & 31;
    wsh[kk][mm] = W[(m0 + mm) * 32 + kk];
  }
  __syncthreads();
#pragma unroll 8
  for (int kk = 0; kk < 32; kk++) {
    float a = wsh[kk][m];
    float4 b4 = *(const float4*)&xs[kk][ng * 4];
    acc[0] = fmaf(a, b4.x, acc[0]);
    acc[1] = fmaf(a, b4.y, acc[1]);
    acc[2] = fmaf(a, b4.z, acc[2]);
    acc[3] = fmaf(a, b4.w, acc[3]);
  }
  int row = m0 + m;
  float bv = bias[row];
  float4 o = make_float4(acc[0] + bv, acc[1] + bv, acc[2] + bv, acc[3] + bv);
  *(float4*)&C[row * NPIX + n0 + ng * 4] = o;
}

// ---------------------------------------------------------------------------
// Split helpers: fp32 -> truncated bf16 hi + bf16(lo) with lo = x - f32(hi).
__device__ __forceinline__ unsigned int split_pack(float x) {
  // returns (hi16) | (lo16 << 16)
  unsigned int u = __float_as_uint(x);
  unsigned int hif = u & 0xffff0000u;
  float lof = x - __uint_as_float(hif);
  unsigned int lu = __float_as_uint(lof);
  return (u >> 16) | (lu & 0xffff0000u);
}

// ---------------------------------------------------------------------------
// qkvmod: modulate qkv with (g,bt); q += alpha*(pooled-mean); q *= QSCALE;
// emit bf16 hi/lo packed operand arrays:
//  qhl/khl[h][n][16 bf16]: shorts 0..7 = hi(d), 8..15 = lo(d)
//  vth/vtl[h][d][n] bf16 (transposed for PV B-fragments)
__global__ __launch_bounds__(256) void qkvmod_kernel(
    const float* __restrict__ qkv, const float* __restrict__ g,
    const float* __restrict__ bt, const float* __restrict__ pooled,
    const float* __restrict__ sum, const float* __restrict__ alpha,
    unsigned int* __restrict__ qhl, unsigned int* __restrict__ khl,
    unsigned short* __restrict__ vth, unsigned short* __restrict__ vtl) {
  const float QSCALE = 0.35355339059327376f * 1.4426950408889634f;
  int t = blockIdx.x * 256 + threadIdx.x;  // h*4096+n
  int n = t & 4095, h = t >> 12;
  float mean = sum[0] * (1.f / 4096.f);
  float iv = alpha[0] * (pooled[n] - mean);
#pragma unroll
  for (int part = 0; part < 3; part++) {
    float val[8];
#pragma unroll
    for (int d = 0; d < 8; d++) {
      int c = h * 8 + d;
      float r = fmaf(g[c * NPIX + n], qkv[(part * 64 + c) * NPIX + n],
                     bt[c * NPIX + n]);
      if (part == 0) r = (r + iv) * QSCALE;
      val[d] = r;
    }
    if (part < 2) {
      unsigned int pk[8];
#pragma unroll
      for (int d = 0; d < 8; d++) pk[d] = split_pack(val[d]);
      // row: shorts 0..7 = hi, 8..15 = lo  -> dwords: [hi01,hi23,hi45,hi67,
      //                                               lo01,lo23,lo45,lo67]
      uintx4 lohalf, hihalf;
      hihalf.x = (pk[0] & 0xffffu) | (pk[1] << 16);
      hihalf.y = (pk[2] & 0xffffu) | (pk[3] << 16);
      hihalf.z = (pk[4] & 0xffffu) | (pk[5] << 16);
      hihalf.w = (pk[6] & 0xffffu) | (pk[7] << 16);
      lohalf.x = (pk[0] >> 16) | (pk[1] & 0xffff0000u);
      lohalf.y = (pk[2] >> 16) | (pk[3] & 0xffff0000u);
      lohalf.z = (pk[4] >> 16) | (pk[5] & 0xffff0000u);
      lohalf.w = (pk[6] >> 16) | (pk[7] & 0xffff0000u);
      unsigned int* dst = (part == 0 ? qhl : khl) + (size_t)(h * NPIX + n) * 8;
      *(uintx4*)dst = hihalf;
      *(uintx4*)(dst + 4) = lohalf;
    } else {
#pragma unroll
      for (int d = 0; d < 8; d++) {
        unsigned int pk = split_pack(val[d]);
        vth[(h * 8 + d) * NPIX + n] = (unsigned short)(pk & 0xffffu);
        vtl[(h * 8 + d) * NPIX + n] = (unsigned short)(pk >> 16);
      }
    }
  }
}

// ---------------------------------------------------------------------------
// MFMA flash attention. grid (64 i-tiles, 8 heads); block 256 (4 waves).
// Wave w owns rows i0+w*16..+15; full j sweep (no partials/combine).
// S: one 16x16x32 MFMA per 16x16 tile computes (qhi+qlo)(khi+klo) exactly
//    via K-slot packing [qhi,qhi,qlo,qlo] x [khi,klo,khi,klo].
// PV: p split to bf16 hi/lo through per-wave LDS (C-layout -> A-layout),
//     3 compensated MFMAs vs vt_hi/vt_lo.
__global__ __launch_bounds__(256, 2) void attn_kernel(
    const unsigned short* __restrict__ qhl,
    const unsigned short* __restrict__ khl,
    const unsigned short* __restrict__ vth,
    const unsigned short* __restrict__ vtl, float* __restrict__ attno) {
  __shared__ unsigned int pl[4][16 * 36];  // packed (hi|lo<<16), row stride 36
  int tid = threadIdx.x;
  int wave = tid >> 6, lane = tid & 63;
  int g = lane >> 4, c = lane & 15;
  int h = blockIdx.y;
  int i0 = blockIdx.x * 64 + wave * 16;
  unsigned int* plw = &pl[wave][0];

  // q A-fragment: A[m=c][k=g*8+j]; slots: g0,g1 -> hi, g2,g3 -> lo
  const bf16x8 qa =
      *(const bf16x8*)(qhl + (size_t)(h * NPIX + i0 + c) * 16 + (g >> 1) * 8);
  int dd = c & 7;
  const unsigned short* vthp = vth + (size_t)(h * 8 + dd) * NPIX + g * 8;
  const unsigned short* vtlp = vtl + (size_t)(h * 8 + dd) * NPIX + g * 8;
  const unsigned short* khp = khl + (size_t)(h * NPIX + c) * 16 + (g & 1) * 8;

  floatx4 out = {0.f, 0.f, 0.f, 0.f};
  float m[4], l[4];
#pragma unroll
  for (int r = 0; r < 4; r++) {
    m[r] = -INFINITY;
    l[r] = 0.f;
  }
  floatx4 zero4 = {0.f, 0.f, 0.f, 0.f};

  // prefetch tile 0
  bf16x8 bk0 = *(const bf16x8*)(khp);
  bf16x8 bk1 = *(const bf16x8*)(khp + 16 * 16);
  bf16x8 bvh = *(const bf16x8*)(vthp);
  bf16x8 bvl = *(const bf16x8*)(vtlp);

  for (int jt = 0; jt < NPIX; jt += 32) {
    int jn = (jt + 32) & (NPIX - 1);
    bf16x8 nbk0 = *(const bf16x8*)(khp + (size_t)jn * 16);
    bf16x8 nbk1 = *(const bf16x8*)(khp + (size_t)(jn + 16) * 16);
    bf16x8 nbvh = *(const bf16x8*)(vthp + jn);
    bf16x8 nbvl = *(const bf16x8*)(vtlp + jn);

    floatx4 s0 = __builtin_amdgcn_mfma_f32_16x16x32_bf16(qa, bk0, zero4, 0, 0, 0);
    floatx4 s1 = __builtin_amdgcn_mfma_f32_16x16x32_bf16(qa, bk1, zero4, 0, 0, 0);

    // row max over the 32 j's (rows = g*4+r, shared by 16 lanes of group g)
    float cm[4];
#pragma unroll
    for (int r = 0; r < 4; r++) cm[r] = fmaxf(s0[r], s1[r]);
#pragma unroll
    for (int mask = 1; mask < 16; mask <<= 1)
#pragma unroll
      for (int r = 0; r < 4; r++)
        cm[r] = fmaxf(cm[r], __shfl_xor(cm[r], mask));

#pragma unroll
    for (int r = 0; r < 4; r++) {
      float mn = fmaxf(m[r], cm[r]);
      float co = __builtin_amdgcn_exp2f(m[r] - mn);
      m[r] = mn;
      l[r] *= co;
      out[r] *= co;
      float p0 = __builtin_amdgcn_exp2f(s0[r] - mn);
      float p1 = __builtin_amdgcn_exp2f(s1[r] - mn);
      l[r] += p0 + p1;
      int row = g * 4 + r;
      plw[row * 36 + c] = split_pack(p0);
      plw[row * 36 + 16 + c] = split_pack(p1);
    }
    // read back A-fragments: A[m=c][k=g*8+jj]
    uintx4 ra = *(uintx4*)&plw[c * 36 + g * 8];
    uintx4 rb = *(uintx4*)&plw[c * 36 + g * 8 + 4];
    uintx4 hih, loh;
    hih.x = (ra.x & 0xffffu) | (ra.y << 16);
    hih.y = (ra.z & 0xffffu) | (ra.w << 16);
    hih.z = (rb.x & 0xffffu) | (rb.y << 16);
    hih.w = (rb.z & 0xffffu) | (rb.w << 16);
    loh.x = (ra.x >> 16) | (ra.y & 0xffff0000u);
    loh.y = (ra.z >> 16) | (ra.w & 0xffff0000u);
    loh.z = (rb.x >> 16) | (rb.w & 0xffff0000u & 0u) | (rb.w & 0xffff0000u);  // placeholder fixed below
    loh.z = (rb.x >> 16) | (rb.y & 0xffff0000u);
    loh.w = (rb.z >> 16) | (rb.w & 0xffff0000u);
    bf16x8 aph = __builtin_bit_cast(bf16x8, hih);
    bf16x8 apl = __builtin_bit_cast(bf16x8, loh);

    out = __builtin_amdgcn_mfma_f32_16x16x32_bf16(aph, bvh, out, 0, 0, 0);
    out = __builtin_amdgcn_mfma_f32_16x16x32_bf16(aph, bvl, out, 0, 0, 0);
    out = __builtin_amdgcn_mfma_f32_16x16x32_bf16(apl, bvh, out, 0, 0, 0);

    bk0 = nbk0; bk1 = nbk1; bvh = nbvh; bvl = nbvl;
  }
  // reduce l across the 16 lanes of each group (row sums)
#pragma unroll
  for (int mask = 1; mask < 16; mask <<= 1)
#pragma unroll
    for (int r = 0; r < 4; r++) l[r] += __shfl_xor(l[r], mask);
  if (c < 8) {
#pragma unroll
    for (int r = 0; r < 4; r++) {
      int i = i0 + g * 4 + r;
      attno[(h * 8 + c) * NPIX + i] = out[r] / l[r];
    }
  }
}

// ---------------------------------------------------------------------------
// Depthwise 3x3 + exact GELU (unchanged from r2).
__global__ __launch_bounds__(256) void dw_gelu_kernel(
    const float* __restrict__ f1, const float* __restrict__ w,
    const float* __restrict__ b, float* __restrict__ f2) {
  int t = blockIdx.x * 256 + threadIdx.x;
  int c = t >> 10, pq = t & 1023;
  int py = pq >> 4, px0 = (pq & 15) << 2;
  const float* base = f1 + c * NPIX;
  float wv[9];
#pragma unroll
  for (int i = 0; i < 9; i++) wv[i] = w[c * 9 + i];
  float bc = b[c];
  float a[4] = {bc, bc, bc, bc};
#pragma unroll
  for (int dy = 0; dy < 3; dy++) {
    int y = py + dy - 1;
    if (y < 0 || y > 63) continue;
    const float* row = base + y * IMG + px0;
    float4 mid = *(const float4*)row;
    float left = (px0 > 0) ? row[-1] : 0.f;
    float right = (px0 < 60) ? row[4] : 0.f;
    float win[6] = {left, mid.x, mid.y, mid.z, mid.w, right};
#pragma unroll
    for (int o = 0; o < 4; o++)
#pragma unroll
      for (int dx = 0; dx < 3; dx++)
        a[o] = fmaf(wv[dy * 3 + dx], win[o + dx], a[o]);
  }
  float4 o4;
  float* op = &o4.x;
#pragma unroll
  for (int o = 0; o < 4; o++)
    op[o] = 0.5f * a[o] * (1.f + erff(a[o] * 0.70710678118654752f));
  *(float4*)&f2[c * NPIX + py * IMG + px0] = o4;
}

// ---------------------------------------------------------------------------
extern "C" void kernel_launch(void* const* d_in, const int* in_sizes, int n_in,
                              void* d_out, int out_size, void* d_ws,
                              size_t ws_size, hipStream_t stream) {
  const float* x      = (const float*)d_in[0];
  const float* luma   = (const float*)d_in[1];
  const float* ln1_w  = (const float*)d_in[2];
  const float* ln1_b  = (const float*)d_in[3];
  const float* qkv_w  = (const float*)d_in[4];
  const float* qkv_b  = (const float*)d_in[5];
  const float* proj_w = (const float*)d_in[6];
  const float* proj_b = (const float*)d_in[7];
  const float* lc1_w  = (const float*)d_in[8];
  const float* lc1_b  = (const float*)d_in[9];
  const float* lc2_w  = (const float*)d_in[10];
  const float* lc2_b  = (const float*)d_in[11];
  const float* gam_w  = (const float*)d_in[12];
  const float* gam_b  = (const float*)d_in[13];
  const float* bet_w  = (const float*)d_in[14];
  const float* bet_b  = (const float*)d_in[15];
  const float* alpha  = (const float*)d_in[16];
  const float* ln2_w  = (const float*)d_in[17];
  const float* ln2_b  = (const float*)d_in[18];
  const float* ffn1_w = (const float*)d_in[19];
  const float* ffn1_b = (const float*)d_in[20];
  const float* dw_w   = (const float*)d_in[21];
  const float* dw_b   = (const float*)d_in[22];
  const float* ffn2_w = (const float*)d_in[23];
  const float* ffn2_b = (const float*)d_in[24];
  float* out = (float*)d_out;

  float* w = (float*)d_ws;
  float* pooled = w + 0;                    // 4096
  float* sum    = w + 4096;                 // 64
  unsigned int*   qhl = (unsigned int*)(w + 4160);      // 262144 f
  unsigned int*   khl = (unsigned int*)(w + 266304);    // 262144 f
  unsigned short* vth = (unsigned short*)(w + 528448);  // 131072 f
  unsigned short* vtl = (unsigned short*)(w + 659520);  // 131072 f
  float* attno = w + 790592;   // 262144
  float* x1    = w + 1052736;  // 262144
  float* f1    = w + 1314880;  // 1048576
  float* f2    = w + 2363456;  // 1048576
  // scratch overlays (dead before their hosts are written)
  float* h1  = f1 + 0;       // 131072
  float* h2  = f1 + 131072;  // 131072
  float* g   = f1 + 262144;  // 262144
  float* bt  = f1 + 524288;  // 262144
  float* qkv = f2 + 0;       // 786432

  hipMemsetAsync(sum, 0, sizeof(float), stream);
  // luma conditioning branch
  lc1_kernel<<<16, 256, 0, stream>>>(luma, lc1_w, lc1_b, h1, pooled, sum);
  lc2_kernel<<<dim3(16, 8), 256, 0, stream>>>(h1, lc2_w, lc2_b, h2);
  gemm_gb_kernel<<<dim3(64, 8), 256, 0, stream>>>(gam_w, bet_w, h2, gam_b,
                                                  bet_b, g, bt);
  // attention branch
  ln_gemm_kernel<<<dim3(64, 3), 256, 0, stream>>>(x, ln1_w, ln1_b, qkv_w,
                                                  qkv_b, qkv);
  qkvmod_kernel<<<128, 256, 0, stream>>>(qkv, g, bt, pooled, sum, alpha, qhl,
                                         khl, vth, vtl);
  attn_kernel<<<dim3(64, 8), 256, 0, stream>>>(
      (const unsigned short*)qhl, (const unsigned short*)khl, vth, vtl, attno);
  gemm16_kernel<<<dim3(64, 4), 256, 0, stream>>>(proj_w, attno, proj_b, x, x1,
                                                 64);
  // FFN branch
  ln_gemm_kernel<<<dim3(64, 4), 256, 0, stream>>>(x1, ln2_w, ln2_b, ffn1_w,
                                                  ffn1_b, f1);
  dw_gelu_kernel<<<1024, 256, 0, stream>>>(f1, dw_w, dw_b, f2);
  gemm16_kernel<<<dim3(64, 4), 256, 0, stream>>>(ffn2_w, f2, ffn2_b, x1, out,
                                                 256);
}

// Round 4
// 273.120 us; speedup vs baseline: 1.0886x; 1.0886x over previous
//
#include <hip/hip_runtime.h>
#include <math.h>

// B=1, C=64, H=W=64, N=4096, heads=8, dh=8, inner=64, hid_lc=32, hid_f=256.
#define NPIX 4096
#define IMG 64

typedef __attribute__((ext_vector_type(8))) short bf16x8;
typedef __attribute__((ext_vector_type(4))) float floatx4;
typedef __attribute__((ext_vector_type(4))) unsigned int uintx4;

// fp32 -> (hi bf16 in low16) | (lo bf16 in high16), lo = x - f32(hi)
__device__ __forceinline__ unsigned int split_pack(float x) {
  unsigned int u = __float_as_uint(x);
  unsigned int hif = u & 0xffff0000u;
  float lof = x - __uint_as_float(hif);
  return (u >> 16) | (__float_as_uint(lof) & 0xffff0000u);
}

// ---------------------------------------------------------------------------
// Fused luma branch: recompute h1=relu(conv3x3(luma)) per-tile (halo), then
// lc2 conv -> h2. Blocks with ocg==0 also produce pooled + atomic sum.
__global__ __launch_bounds__(256) void lc_fused_kernel(
    const float* __restrict__ luma, const float* __restrict__ w1,
    const float* __restrict__ b1, const float* __restrict__ w2,
    const float* __restrict__ b2, float* __restrict__ h2,
    float* __restrict__ pooled, float* __restrict__ sum) {
  __shared__ float tin[32][324];  // h1 on 18x18 halo per ic
  __shared__ float swt[4][32][9];
  __shared__ float red[256];
  int tile = blockIdx.x, ocg = blockIdx.y;
  int ty0 = (tile >> 2) * 16, tx0 = (tile & 3) * 16;
  int tid = threadIdx.x;
  for (int idx = tid; idx < 32 * 324; idx += 256) {
    int ic = idx / 324, pos = idx - ic * 324;
    int py = pos / 18, px = pos - py * 18;
    int gy = ty0 + py - 1, gx = tx0 + px - 1;
    float v = 0.f;
    if (gy >= 0 && gy < IMG && gx >= 0 && gx < IMG) {
      float s = b1[ic];
#pragma unroll
      for (int dy = 0; dy < 3; dy++)
#pragma unroll
        for (int dx = 0; dx < 3; dx++) {
          int y = gy + dy - 1, x = gx + dx - 1;
          if (y >= 0 && y < IMG && x >= 0 && x < IMG)
            s = fmaf(w1[ic * 9 + dy * 3 + dx], luma[y * IMG + x], s);
        }
      v = fmaxf(s, 0.f);
    }
    tin[ic][pos] = v;
  }
  for (int idx = tid; idx < 4 * 32 * 9; idx += 256) {
    int o = idx / 288, r = idx - o * 288;
    swt[o][r / 9][r % 9] = w2[(ocg * 4 + o) * 288 + r];
  }
  __syncthreads();
  int ly = tid >> 4, lx = tid & 15;
  int p = (ty0 + ly) * IMG + tx0 + lx;
  float acc[4];
#pragma unroll
  for (int o = 0; o < 4; o++) acc[o] = b2[ocg * 4 + o];
  for (int ic = 0; ic < 32; ic++) {
    float v[9];
#pragma unroll
    for (int dy = 0; dy < 3; dy++)
#pragma unroll
      for (int dx = 0; dx < 3; dx++)
        v[dy * 3 + dx] = tin[ic][(ly + dy) * 18 + lx + dx];
#pragma unroll
    for (int o = 0; o < 4; o++)
#pragma unroll
      for (int t = 0; t < 9; t++) acc[o] = fmaf(swt[o][ic][t], v[t], acc[o]);
  }
#pragma unroll
  for (int o = 0; o < 4; o++)
    h2[(ocg * 4 + o) * NPIX + p] = fmaxf(acc[o], 0.f);
  if (ocg == 0) {
    int gy = ty0 + ly, gx = tx0 + lx;
    float sv = 0.f;
#pragma unroll
    for (int dy = 0; dy < 3; dy++)
#pragma unroll
      for (int dx = 0; dx < 3; dx++) {
        int y = gy + dy - 1, x = gx + dx - 1;
        if (y >= 0 && y < IMG && x >= 0 && x < IMG) sv += luma[y * IMG + x];
      }
    float cy = 3.f - (gy == 0 ? 1.f : 0.f) - (gy == 63 ? 1.f : 0.f);
    float cx = 3.f - (gx == 0 ? 1.f : 0.f) - (gx == 63 ? 1.f : 0.f);
    float pv = (cy * cx - sv) * (1.f / 9.f);
    pooled[p] = pv;
    red[tid] = pv;
    __syncthreads();
    for (int st = 128; st > 0; st >>= 1) {
      if (tid < st) red[tid] += red[tid + st];
      __syncthreads();
    }
    if (tid == 0) atomicAdd(sum, red[0]);
  }
}

// ---------------------------------------------------------------------------
// gam+bet in one launch: blockIdx.y<4 -> gam, else bet. K=32.
__global__ __launch_bounds__(256) void gemm_gb_kernel(
    const float* __restrict__ Wg, const float* __restrict__ Wb,
    const float* __restrict__ X, const float* __restrict__ bg,
    const float* __restrict__ bb, float* __restrict__ Cg,
    float* __restrict__ Cb) {
  __shared__ float xs[32][64];
  __shared__ float wsh[32][16];
  int yy = blockIdx.y;
  const float* W = yy < 4 ? Wg : Wb;
  const float* bias = yy < 4 ? bg : bb;
  float* C = yy < 4 ? Cg : Cb;
  int n0 = blockIdx.x * 64, m0 = (yy & 3) * 16;
  int tid = threadIdx.x;
  int m = tid >> 4, ng = tid & 15;
  float acc[4] = {};
  {
    int i0 = tid * 2;
    int k = i0 >> 4, nf = (i0 & 15) * 4;
    *(float4*)&xs[k][nf] = *(const float4*)&X[k * NPIX + n0 + nf];
    int i1 = i0 + 1;
    int k1 = i1 >> 4, nf1 = (i1 & 15) * 4;
    *(float4*)&xs[k1][nf1] = *(const float4*)&X[k1 * NPIX + n0 + nf1];
  }
#pragma unroll
  for (int e = tid; e < 512; e += 256) {
    int mm = e >> 5, kk = e & 31;
    wsh[kk][mm] = W[(m0 + mm) * 32 + kk];
  }
  __syncthreads();
#pragma unroll 8
  for (int kk = 0; kk < 32; kk++) {
    float a = wsh[kk][m];
    float4 b4 = *(const float4*)&xs[kk][ng * 4];
    acc[0] = fmaf(a, b4.x, acc[0]);
    acc[1] = fmaf(a, b4.y, acc[1]);
    acc[2] = fmaf(a, b4.z, acc[2]);
    acc[3] = fmaf(a, b4.w, acc[3]);
  }
  int row = m0 + m;
  float bv = bias[row];
  float4 o = make_float4(acc[0] + bv, acc[1] + bv, acc[2] + bv, acc[3] + bv);
  *(float4*)&C[row * NPIX + n0 + ng * 4] = o;
}

// ---------------------------------------------------------------------------
// Fused per-pixel LayerNorm + qkv 1x1 GEMM + modulation + hi/lo split store.
// grid (64 n-blocks, 3 parts). part 0->q, 1->k, 2->v.
__global__ __launch_bounds__(256) void ln_qkv_kernel(
    const float* __restrict__ X, const float* __restrict__ lnw,
    const float* __restrict__ lnb, const float* __restrict__ W,
    const float* __restrict__ bias, const float* __restrict__ gmod,
    const float* __restrict__ bmod, const float* __restrict__ pooled,
    const float* __restrict__ sum, const float* __restrict__ alpha,
    unsigned short* __restrict__ qhl, unsigned short* __restrict__ khl,
    unsigned short* __restrict__ vth, unsigned short* __restrict__ vtl) {
  const float QSCALE = 0.35355339059327376f * 1.4426950408889634f;
  __shared__ float xs[64][64];
  __shared__ float wsh[64][64];
  __shared__ float psum[4][64];
  __shared__ float mu[64];
  __shared__ float rs[64];
  int n0 = blockIdx.x * 64, m0 = blockIdx.y * 64;
  int part = blockIdx.y;
  int tid = threadIdx.x;
  int c = tid >> 2, pg = (tid & 3) * 16;
  {
    const float4* src = (const float4*)&X[c * NPIX + n0 + pg];
    float4* dst = (float4*)&xs[c][pg];
    dst[0] = src[0]; dst[1] = src[1]; dst[2] = src[2]; dst[3] = src[3];
  }
  {
    int m = tid >> 2, kg = (tid & 3) * 16;
    const float4* wr = (const float4*)&W[(m0 + m) * 64 + kg];
    float4 w0 = wr[0], w1 = wr[1], w2 = wr[2], w3 = wr[3];
    float wv[16] = {w0.x, w0.y, w0.z, w0.w, w1.x, w1.y, w1.z, w1.w,
                    w2.x, w2.y, w2.z, w2.w, w3.x, w3.y, w3.z, w3.w};
#pragma unroll
    for (int j = 0; j < 16; j++) wsh[kg + j][m] = wv[j];
  }
  __syncthreads();
  int px = tid & 63, qq = tid >> 6;
  float s = 0.f;
#pragma unroll
  for (int cc = 0; cc < 16; cc++) s += xs[qq * 16 + cc][px];
  psum[qq][px] = s;
  __syncthreads();
  if (tid < 64) {
    float t = psum[0][tid] + psum[1][tid] + psum[2][tid] + psum[3][tid];
    mu[tid] = t * (1.f / 64.f);
  }
  __syncthreads();
  float mm = mu[px];
  s = 0.f;
#pragma unroll
  for (int cc = 0; cc < 16; cc++) {
    float d = xs[qq * 16 + cc][px] - mm;
    s = fmaf(d, d, s);
  }
  psum[qq][px] = s;
  __syncthreads();
  if (tid < 64) {
    float t = psum[0][tid] + psum[1][tid] + psum[2][tid] + psum[3][tid];
    rs[tid] = rsqrtf(t * (1.f / 64.f) + 1e-5f);
  }
  __syncthreads();
  {
    float wc = lnw[c], bc = lnb[c];
#pragma unroll
    for (int j = 0; j < 16; j++) {
      int p = pg + j;
      xs[c][p] = (xs[c][p] - mu[p]) * rs[p] * wc + bc;
    }
  }
  __syncthreads();
  int tx = tid & 15, ty = tid >> 4;
  float acc[4][4] = {};
#pragma unroll 8
  for (int kk = 0; kk < 64; kk++) {
    float4 a = *(const float4*)&wsh[kk][ty * 4];
    float4 b4 = *(const float4*)&xs[kk][tx * 4];
    float av[4] = {a.x, a.y, a.z, a.w};
    float bv[4] = {b4.x, b4.y, b4.z, b4.w};
#pragma unroll
    for (int im = 0; im < 4; im++)
#pragma unroll
      for (int in = 0; in < 4; in++)
        acc[im][in] = fmaf(av[im], bv[in], acc[im][in]);
  }
  // epilogue: bias + modulation (+ q extras), hi/lo split, store
  float val[4][4];
#pragma unroll
  for (int im = 0; im < 4; im++) {
    int cc = ty * 4 + im;
    float bv = bias[m0 + cc];
    const float4 gv = *(const float4*)&gmod[cc * NPIX + n0 + tx * 4];
    const float4 bm = *(const float4*)&bmod[cc * NPIX + n0 + tx * 4];
    float ga[4] = {gv.x, gv.y, gv.z, gv.w};
    float ba[4] = {bm.x, bm.y, bm.z, bm.w};
#pragma unroll
    for (int in = 0; in < 4; in++)
      val[im][in] = fmaf(ga[in], acc[im][in] + bv, ba[in]);
  }
  if (part == 0) {
    float mean = sum[0] * (1.f / 4096.f);
    float a0 = alpha[0];
    const float4 pv = *(const float4*)&pooled[n0 + tx * 4];
    float iv[4] = {a0 * (pv.x - mean), a0 * (pv.y - mean),
                   a0 * (pv.z - mean), a0 * (pv.w - mean)};
#pragma unroll
    for (int im = 0; im < 4; im++)
#pragma unroll
      for (int in = 0; in < 4; in++)
        val[im][in] = (val[im][in] + iv[in]) * QSCALE;
  }
  if (part < 2) {
    unsigned short* dst = (part == 0) ? qhl : khl;
    int h = ty >> 1, d0 = (ty & 1) * 4;
#pragma unroll
    for (int in = 0; in < 4; in++) {
      int n = n0 + tx * 4 + in;
      unsigned int pk[4];
#pragma unroll
      for (int im = 0; im < 4; im++) pk[im] = split_pack(val[im][in]);
      short4 hi, lo;
      hi.x = (short)(pk[0] & 0xffffu); hi.y = (short)(pk[1] & 0xffffu);
      hi.z = (short)(pk[2] & 0xffffu); hi.w = (short)(pk[3] & 0xffffu);
      lo.x = (short)(pk[0] >> 16); lo.y = (short)(pk[1] >> 16);
      lo.z = (short)(pk[2] >> 16); lo.w = (short)(pk[3] >> 16);
      unsigned short* base = dst + ((size_t)(h * NPIX + n) << 4) + d0;
      *(short4*)base = hi;
      *(short4*)(base + 8) = lo;
    }
  } else {
#pragma unroll
    for (int im = 0; im < 4; im++) {
      int cc = ty * 4 + im;
      unsigned int pk[4];
#pragma unroll
      for (int in = 0; in < 4; in++) pk[in] = split_pack(val[im][in]);
      short4 hi, lo;
      hi.x = (short)(pk[0] & 0xffffu); hi.y = (short)(pk[1] & 0xffffu);
      hi.z = (short)(pk[2] & 0xffffu); hi.w = (short)(pk[3] & 0xffffu);
      lo.x = (short)(pk[0] >> 16); lo.y = (short)(pk[1] >> 16);
      lo.z = (short)(pk[2] >> 16); lo.w = (short)(pk[3] >> 16);
      *(short4*)(vth + (size_t)cc * NPIX + n0 + tx * 4) = hi;
      *(short4*)(vtl + (size_t)cc * NPIX + n0 + tx * 4) = lo;
    }
  }
}

// ---------------------------------------------------------------------------
// MFMA flash attention, S^T formulation. grid (64 i-tiles, 8 heads, 4 jp).
// Wave owns 16 queries; sweeps 1024 j's. S^T = K x Q^T (exact via hi/lo
// K-slot packing). Softmax per-lane (col = query). PV: out^T = V^T x P^T,
// P^T through swizzled per-wave LDS (b128 write/read), 3 indep accumulators.
__global__ __launch_bounds__(256, 6) void attn_kernel(
    const unsigned short* __restrict__ qhl,
    const unsigned short* __restrict__ khl,
    const unsigned short* __restrict__ vth,
    const unsigned short* __restrict__ vtl, float* __restrict__ pacc,
    float* __restrict__ pml) {
  __shared__ unsigned int pl[4][576];  // per wave: 16 rows (i) x 36 (32 j + pad)
  int tid = threadIdx.x;
  int wave = tid >> 6, lane = tid & 63;
  int g = lane >> 4, c = lane & 15;
  int h = blockIdx.y, jp = blockIdx.z;
  int i0 = blockIdx.x * 64 + wave * 16;
  int jbase = jp * 1024;
  unsigned int* plw = pl[wave];
  int sw = c & 3;
  int wA = c * 36 + ((g ^ sw) << 2);                          // tile0 write
  int rA = c * 36 + ((g >> 1) << 4) + ((((g << 1) & 3) ^ sw) << 2);
  int rB = c * 36 + ((g >> 1) << 4) + (((((g << 1) + 1) & 3) ^ sw) << 2);

  const bf16x8 qB =
      *(const bf16x8*)(qhl + (((size_t)(h * NPIX + i0 + c)) << 4) + ((g & 1) << 3));
  const unsigned short* kp =
      khl + (((size_t)(h * NPIX + jbase + c)) << 4) + ((g >> 1) << 3);
  const unsigned short* vhp =
      vth + (size_t)(h * 8 + (c & 7)) * NPIX + jbase + (g << 3);
  const unsigned short* vlp =
      vtl + (size_t)(h * 8 + (c & 7)) * NPIX + jbase + (g << 3);

  floatx4 zero4 = {0.f, 0.f, 0.f, 0.f};
  floatx4 acc0 = zero4, acc1 = zero4, acc2 = zero4;
  float m = -INFINITY, l = 0.f;

  for (int jt = 0; jt < 32; ++jt) {
    bf16x8 ka0 = *(const bf16x8*)kp;
    bf16x8 ka1 = *(const bf16x8*)(kp + 256);
    bf16x8 avh = *(const bf16x8*)vhp;
    bf16x8 avl = *(const bf16x8*)vlp;
    kp += 512;
    vhp += 32;
    vlp += 32;
    floatx4 s0 = __builtin_amdgcn_mfma_f32_16x16x32_bf16(ka0, qB, zero4, 0, 0, 0);
    floatx4 s1 = __builtin_amdgcn_mfma_f32_16x16x32_bf16(ka1, qB, zero4, 0, 0, 0);
    float cm = fmaxf(fmaxf(fmaxf(s0[0], s0[1]), fmaxf(s0[2], s0[3])),
                     fmaxf(fmaxf(s1[0], s1[1]), fmaxf(s1[2], s1[3])));
    cm = fmaxf(cm, __shfl_xor(cm, 16));
    cm = fmaxf(cm, __shfl_xor(cm, 32));
    float mn = fmaxf(m, cm);
    float co = __builtin_amdgcn_exp2f(m - mn);
    m = mn;
    l *= co;
    acc0 *= co;
    acc1 *= co;
    acc2 *= co;
    uintx4 w0, w1;
    float ps = 0.f;
    {
      float p0 = __builtin_amdgcn_exp2f(s0[0] - mn);
      float p1 = __builtin_amdgcn_exp2f(s0[1] - mn);
      float p2 = __builtin_amdgcn_exp2f(s0[2] - mn);
      float p3 = __builtin_amdgcn_exp2f(s0[3] - mn);
      ps += (p0 + p1) + (p2 + p3);
      w0.x = split_pack(p0); w0.y = split_pack(p1);
      w0.z = split_pack(p2); w0.w = split_pack(p3);
      p0 = __builtin_amdgcn_exp2f(s1[0] - mn);
      p1 = __builtin_amdgcn_exp2f(s1[1] - mn);
      p2 = __builtin_amdgcn_exp2f(s1[2] - mn);
      p3 = __builtin_amdgcn_exp2f(s1[3] - mn);
      ps += (p0 + p1) + (p2 + p3);
      w1.x = split_pack(p0); w1.y = split_pack(p1);
      w1.z = split_pack(p2); w1.w = split_pack(p3);
    }
    l += ps;
    *(uintx4*)&plw[wA] = w0;
    *(uintx4*)&plw[wA + 16] = w1;
    uintx4 da = *(uintx4*)&plw[rA];
    uintx4 db = *(uintx4*)&plw[rB];
    uintx4 hi4, lo4;
    hi4.x = (da.x & 0xffffu) | (da.y << 16);
    hi4.y = (da.z & 0xffffu) | (da.w << 16);
    hi4.z = (db.x & 0xffffu) | (db.y << 16);
    hi4.w = (db.z & 0xffffu) | (db.w << 16);
    lo4.x = (da.x >> 16) | (da.y & 0xffff0000u);
    lo4.y = (da.z >> 16) | (da.w & 0xffff0000u);
    lo4.z = (db.x >> 16) | (db.y & 0xffff0000u);
    lo4.w = (db.z >> 16) | (db.w & 0xffff0000u);
    bf16x8 phi = __builtin_bit_cast(bf16x8, hi4);
    bf16x8 plo = __builtin_bit_cast(bf16x8, lo4);
    acc0 = __builtin_amdgcn_mfma_f32_16x16x32_bf16(avh, phi, acc0, 0, 0, 0);
    acc1 = __builtin_amdgcn_mfma_f32_16x16x32_bf16(avl, phi, acc1, 0, 0, 0);
    acc2 = __builtin_amdgcn_mfma_f32_16x16x32_bf16(avh, plo, acc2, 0, 0, 0);
  }
  l += __shfl_xor(l, 16);
  l += __shfl_xor(l, 32);
  floatx4 o = acc0 + acc1 + acc2;
  if (g < 2) {
    size_t base = (size_t)((jp * 8 + h) * NPIX + i0 + c);
    *(float4*)&pacc[base * 8 + g * 4] = make_float4(o[0], o[1], o[2], o[3]);
    if (g == 0) *(float2*)&pml[base * 2] = make_float2(m, l);
  }
}

// Combine 4 j-partitions; write attno[c=h*8+d][n].
__global__ __launch_bounds__(256) void combine_kernel(
    const float* __restrict__ pacc, const float* __restrict__ pml,
    float* __restrict__ attno) {
  int t = blockIdx.x * 256 + threadIdx.x;  // h*4096+n
  int n = t & 4095, h = t >> 12;
  float M = -INFINITY;
#pragma unroll
  for (int p = 0; p < 4; p++)
    M = fmaxf(M, pml[(size_t)((p * 8 + h) * NPIX + n) * 2]);
  float L = 0.f, o[8] = {};
#pragma unroll
  for (int p = 0; p < 4; p++) {
    size_t base = (size_t)((p * 8 + h) * NPIX + n);
    float mm = pml[base * 2], ll = pml[base * 2 + 1];
    float cc = __builtin_amdgcn_exp2f(mm - M);
    L = fmaf(ll, cc, L);
    const float4 a0 = *(const float4*)&pacc[base * 8];
    const float4 a1 = *(const float4*)&pacc[base * 8 + 4];
    o[0] = fmaf(a0.x, cc, o[0]); o[1] = fmaf(a0.y, cc, o[1]);
    o[2] = fmaf(a0.z, cc, o[2]); o[3] = fmaf(a0.w, cc, o[3]);
    o[4] = fmaf(a1.x, cc, o[4]); o[5] = fmaf(a1.y, cc, o[5]);
    o[6] = fmaf(a1.z, cc, o[6]); o[7] = fmaf(a1.w, cc, o[7]);
  }
  float inv = 1.f / L;
#pragma unroll
  for (int d = 0; d < 8; d++) attno[(h * 8 + d) * NPIX + n] = o[d] * inv;
}

// ---------------------------------------------------------------------------
// Plain fused LayerNorm + 1x1 GEMM (fp32 out) for ffn1.
__global__ __launch_bounds__(256) void ln_gemm_kernel(
    const float* __restrict__ X, const float* __restrict__ lnw,
    const float* __restrict__ lnb, const float* __restrict__ W,
    const float* __restrict__ bias, float* __restrict__ C) {
  __shared__ float xs[64][64];
  __shared__ float wsh[64][64];
  __shared__ float psum[4][64];
  __shared__ float mu[64];
  __shared__ float rs[64];
  int n0 = blockIdx.x * 64, m0 = blockIdx.y * 64;
  int tid = threadIdx.x;
  int c = tid >> 2, pg = (tid & 3) * 16;
  {
    const float4* src = (const float4*)&X[c * NPIX + n0 + pg];
    float4* dst = (float4*)&xs[c][pg];
    dst[0] = src[0]; dst[1] = src[1]; dst[2] = src[2]; dst[3] = src[3];
  }
  {
    int m = tid >> 2, kg = (tid & 3) * 16;
    const float4* wr = (const float4*)&W[(m0 + m) * 64 + kg];
    float4 w0 = wr[0], w1 = wr[1], w2 = wr[2], w3 = wr[3];
    float wv[16] = {w0.x, w0.y, w0.z, w0.w, w1.x, w1.y, w1.z, w1.w,
                    w2.x, w2.y, w2.z, w2.w, w3.x, w3.y, w3.z, w3.w};
#pragma unroll
    for (int j = 0; j < 16; j++) wsh[kg + j][m] = wv[j];
  }
  __syncthreads();
  int px = tid & 63, qq = tid >> 6;
  float s = 0.f;
#pragma unroll
  for (int cc = 0; cc < 16; cc++) s += xs[qq * 16 + cc][px];
  psum[qq][px] = s;
  __syncthreads();
  if (tid < 64) {
    float t = psum[0][tid] + psum[1][tid] + psum[2][tid] + psum[3][tid];
    mu[tid] = t * (1.f / 64.f);
  }
  __syncthreads();
  float mm = mu[px];
  s = 0.f;
#pragma unroll
  for (int cc = 0; cc < 16; cc++) {
    float d = xs[qq * 16 + cc][px] - mm;
    s = fmaf(d, d, s);
  }
  psum[qq][px] = s;
  __syncthreads();
  if (tid < 64) {
    float t = psum[0][tid] + psum[1][tid] + psum[2][tid] + psum[3][tid];
    rs[tid] = rsqrtf(t * (1.f / 64.f) + 1e-5f);
  }
  __syncthreads();
  {
    float wc = lnw[c], bc = lnb[c];
#pragma unroll
    for (int j = 0; j < 16; j++) {
      int p = pg + j;
      xs[c][p] = (xs[c][p] - mu[p]) * rs[p] * wc + bc;
    }
  }
  __syncthreads();
  int tx = tid & 15, ty = tid >> 4;
  float acc[4][4] = {};
#pragma unroll 8
  for (int kk = 0; kk < 64; kk++) {
    float4 a = *(const float4*)&wsh[kk][ty * 4];
    float4 b4 = *(const float4*)&xs[kk][tx * 4];
    float av[4] = {a.x, a.y, a.z, a.w};
    float bv[4] = {b4.x, b4.y, b4.z, b4.w};
#pragma unroll
    for (int im = 0; im < 4; im++)
#pragma unroll
      for (int in = 0; in < 4; in++)
        acc[im][in] = fmaf(av[im], bv[in], acc[im][in]);
  }
#pragma unroll
  for (int im = 0; im < 4; im++) {
    int mrow = m0 + ty * 4 + im;
    float bv = bias[mrow];
    float4 o = make_float4(acc[im][0] + bv, acc[im][1] + bv, acc[im][2] + bv,
                           acc[im][3] + bv);
    *(float4*)&C[mrow * NPIX + n0 + tx * 4] = o;
  }
}

// ---------------------------------------------------------------------------
// Thin GEMM, 16m x 32n tiles: C = W[M][K]*X + bias (+resid). grid (128, M/16).
__global__ __launch_bounds__(256) void gemm16_kernel(
    const float* __restrict__ W, const float* __restrict__ X,
    const float* __restrict__ bias, const float* __restrict__ resid,
    float* __restrict__ C, int K) {
  __shared__ float xs[32][32];
  __shared__ float wsh[32][16];
  int n0 = blockIdx.x * 32, m0 = blockIdx.y * 16;
  int tid = threadIdx.x;
  int m = tid >> 4, np = (tid & 15) * 2;
  float acc0 = 0.f, acc1 = 0.f;
  for (int k0 = 0; k0 < K; k0 += 32) {
    {
      int k = tid >> 3, nf = (tid & 7) * 4;
      *(float4*)&xs[k][nf] = *(const float4*)&X[(k0 + k) * NPIX + n0 + nf];
    }
#pragma unroll
    for (int e = tid; e < 512; e += 256) {
      int kk = e >> 4, mm = e & 15;
      wsh[kk][mm] = W[(m0 + mm) * K + k0 + kk];
    }
    __syncthreads();
#pragma unroll 8
    for (int kk = 0; kk < 32; kk++) {
      float a = wsh[kk][m];
      float2 b2 = *(const float2*)&xs[kk][np];
      acc0 = fmaf(a, b2.x, acc0);
      acc1 = fmaf(a, b2.y, acc1);
    }
    __syncthreads();
  }
  int row = m0 + m;
  float bv = bias[row];
  float2 o = make_float2(acc0 + bv, acc1 + bv);
  if (resid) {
    const float2 r2 = *(const float2*)&resid[row * NPIX + n0 + np];
    o.x += r2.x;
    o.y += r2.y;
  }
  *(float2*)&C[row * NPIX + n0 + np] = o;
}

// ---------------------------------------------------------------------------
// Depthwise 3x3 + exact GELU; 4 horizontal px/thread.
__global__ __launch_bounds__(256) void dw_gelu_kernel(
    const float* __restrict__ f1, const float* __restrict__ w,
    const float* __restrict__ b, float* __restrict__ f2) {
  int t = blockIdx.x * 256 + threadIdx.x;
  int c = t >> 10, pq = t & 1023;
  int py = pq >> 4, px0 = (pq & 15) << 2;
  const float* base = f1 + c * NPIX;
  float wv[9];
#pragma unroll
  for (int i = 0; i < 9; i++) wv[i] = w[c * 9 + i];
  float bc = b[c];
  float a[4] = {bc, bc, bc, bc};
#pragma unroll
  for (int dy = 0; dy < 3; dy++) {
    int y = py + dy - 1;
    if (y < 0 || y > 63) continue;
    const float* row = base + y * IMG + px0;
    float4 mid = *(const float4*)row;
    float left = (px0 > 0) ? row[-1] : 0.f;
    float right = (px0 < 60) ? row[4] : 0.f;
    float win[6] = {left, mid.x, mid.y, mid.z, mid.w, right};
#pragma unroll
    for (int o = 0; o < 4; o++)
#pragma unroll
      for (int dx = 0; dx < 3; dx++)
        a[o] = fmaf(wv[dy * 3 + dx], win[o + dx], a[o]);
  }
  float4 o4;
  float* op = &o4.x;
#pragma unroll
  for (int o = 0; o < 4; o++)
    op[o] = 0.5f * a[o] * (1.f + erff(a[o] * 0.70710678118654752f));
  *(float4*)&f2[c * NPIX + py * IMG + px0] = o4;
}

// ---------------------------------------------------------------------------
extern "C" void kernel_launch(void* const* d_in, const int* in_sizes, int n_in,
                              void* d_out, int out_size, void* d_ws,
                              size_t ws_size, hipStream_t stream) {
  const float* x      = (const float*)d_in[0];
  const float* luma   = (const float*)d_in[1];
  const float* ln1_w  = (const float*)d_in[2];
  const float* ln1_b  = (const float*)d_in[3];
  const float* qkv_w  = (const float*)d_in[4];
  const float* qkv_b  = (const float*)d_in[5];
  const float* proj_w = (const float*)d_in[6];
  const float* proj_b = (const float*)d_in[7];
  const float* lc1_w  = (const float*)d_in[8];
  const float* lc1_b  = (const float*)d_in[9];
  const float* lc2_w  = (const float*)d_in[10];
  const float* lc2_b  = (const float*)d_in[11];
  const float* gam_w  = (const float*)d_in[12];
  const float* gam_b  = (const float*)d_in[13];
  const float* bet_w  = (const float*)d_in[14];
  const float* bet_b  = (const float*)d_in[15];
  const float* alpha  = (const float*)d_in[16];
  const float* ln2_w  = (const float*)d_in[17];
  const float* ln2_b  = (const float*)d_in[18];
  const float* ffn1_w = (const float*)d_in[19];
  const float* ffn1_b = (const float*)d_in[20];
  const float* dw_w   = (const float*)d_in[21];
  const float* dw_b   = (const float*)d_in[22];
  const float* ffn2_w = (const float*)d_in[23];
  const float* ffn2_b = (const float*)d_in[24];
  float* out = (float*)d_out;

  float* w = (float*)d_ws;
  float* pooled = w + 0;        // 4096
  float* sum    = w + 4096;     // 64
  float* h2     = w + 4160;     // 131072
  float* g      = w + 135232;   // 262144
  float* bt     = w + 397376;   // 262144
  unsigned short* qhl = (unsigned short*)(w + 659520);   // 262144 f
  unsigned short* khl = (unsigned short*)(w + 921664);   // 262144 f
  unsigned short* vth = (unsigned short*)(w + 1183808);  // 131072 f
  unsigned short* vtl = (unsigned short*)(w + 1314880);  // 131072 f
  float* pacc  = w + 1445952;   // 1048576
  float* pml   = w + 2494528;   // 262144
  float* attno = w + 2756672;   // 262144
  float* x1    = w + 3018816;   // 262144
  float* f1    = w + 3280960;   // 1048576
  float* f2    = w + 4329536;   // 1048576

  hipMemsetAsync(sum, 0, sizeof(float), stream);
  lc_fused_kernel<<<dim3(16, 8), 256, 0, stream>>>(luma, lc1_w, lc1_b, lc2_w,
                                                   lc2_b, h2, pooled, sum);
  gemm_gb_kernel<<<dim3(64, 8), 256, 0, stream>>>(gam_w, bet_w, h2, gam_b,
                                                  bet_b, g, bt);
  ln_qkv_kernel<<<dim3(64, 3), 256, 0, stream>>>(
      x, ln1_w, ln1_b, qkv_w, qkv_b, g, bt, pooled, sum, alpha, qhl, khl, vth,
      vtl);
  attn_kernel<<<dim3(64, 8, 4), 256, 0, stream>>>(qhl, khl, vth, vtl, pacc,
                                                  pml);
  combine_kernel<<<128, 256, 0, stream>>>(pacc, pml, attno);
  gemm16_kernel<<<dim3(128, 4), 256, 0, stream>>>(proj_w, attno, proj_b, x, x1,
                                                  64);
  ln_gemm_kernel<<<dim3(64, 4), 256, 0, stream>>>(x1, ln2_w, ln2_b, ffn1_w,
                                                  ffn1_b, f1);
  dw_gelu_kernel<<<1024, 256, 0, stream>>>(f1, dw_w, dw_b, f2);
  gemm16_kernel<<<dim3(128, 4), 256, 0, stream>>>(ffn2_w, f2, ffn2_b, x1, out,
                                                  256);
}

// Round 5
// 265.247 us; speedup vs baseline: 1.1210x; 1.0297x over previous
//
#include <hip/hip_runtime.h>
#include <math.h>

// B=1, C=64, H=W=64, N=4096, heads=8, dh=8, inner=64, hid_lc=32, hid_f=256.
#define NPIX 4096
#define IMG 64

typedef __attribute__((ext_vector_type(8))) short bf16x8;
typedef __attribute__((ext_vector_type(4))) float floatx4;
typedef __attribute__((ext_vector_type(4))) unsigned int uintx4;

// fp32 -> (hi bf16 in low16) | (lo bf16 in high16), lo = x - f32(hi)
__device__ __forceinline__ unsigned int split_pack(float x) {
  unsigned int u = __float_as_uint(x);
  unsigned int hif = u & 0xffff0000u;
  float lof = x - __uint_as_float(hif);
  return (u >> 16) | (__float_as_uint(lof) & 0xffff0000u);
}

// pack hi16 of two floats: low16 = hi16(a), high16 = hi16(b)
__device__ __forceinline__ unsigned int hi_pair(float a, float b) {
  return (__float_as_uint(a) >> 16) | (__float_as_uint(b) & 0xffff0000u);
}

// ---------------------------------------------------------------------------
// Fused luma branch: recompute h1=relu(conv3x3(luma)) per-tile (halo), then
// lc2 conv -> h2. ocg==0 blocks also emit pooled + per-tile partial sums.
__global__ __launch_bounds__(256) void lc_fused_kernel(
    const float* __restrict__ luma, const float* __restrict__ w1,
    const float* __restrict__ b1, const float* __restrict__ w2,
    const float* __restrict__ b2, float* __restrict__ h2,
    float* __restrict__ pooled, float* __restrict__ bsums) {
  __shared__ float tin[32][324];  // h1 on 18x18 halo per ic
  __shared__ float swt[4][32][9];
  __shared__ float red[256];
  int tile = blockIdx.x, ocg = blockIdx.y;
  int ty0 = (tile >> 2) * 16, tx0 = (tile & 3) * 16;
  int tid = threadIdx.x;
  for (int idx = tid; idx < 32 * 324; idx += 256) {
    int ic = idx / 324, pos = idx - ic * 324;
    int py = pos / 18, px = pos - py * 18;
    int gy = ty0 + py - 1, gx = tx0 + px - 1;
    float v = 0.f;
    if (gy >= 0 && gy < IMG && gx >= 0 && gx < IMG) {
      float s = b1[ic];
#pragma unroll
      for (int dy = 0; dy < 3; dy++)
#pragma unroll
        for (int dx = 0; dx < 3; dx++) {
          int y = gy + dy - 1, x = gx + dx - 1;
          if (y >= 0 && y < IMG && x >= 0 && x < IMG)
            s = fmaf(w1[ic * 9 + dy * 3 + dx], luma[y * IMG + x], s);
        }
      v = fmaxf(s, 0.f);
    }
    tin[ic][pos] = v;
  }
  for (int idx = tid; idx < 4 * 32 * 9; idx += 256) {
    int o = idx / 288, r = idx - o * 288;
    swt[o][r / 9][r % 9] = w2[(ocg * 4 + o) * 288 + r];
  }
  __syncthreads();
  int ly = tid >> 4, lx = tid & 15;
  int p = (ty0 + ly) * IMG + tx0 + lx;
  float acc[4];
#pragma unroll
  for (int o = 0; o < 4; o++) acc[o] = b2[ocg * 4 + o];
  for (int ic = 0; ic < 32; ic++) {
    float v[9];
#pragma unroll
    for (int dy = 0; dy < 3; dy++)
#pragma unroll
      for (int dx = 0; dx < 3; dx++)
        v[dy * 3 + dx] = tin[ic][(ly + dy) * 18 + lx + dx];
#pragma unroll
    for (int o = 0; o < 4; o++)
#pragma unroll
      for (int t = 0; t < 9; t++) acc[o] = fmaf(swt[o][ic][t], v[t], acc[o]);
  }
#pragma unroll
  for (int o = 0; o < 4; o++)
    h2[(ocg * 4 + o) * NPIX + p] = fmaxf(acc[o], 0.f);
  if (ocg == 0) {
    int gy = ty0 + ly, gx = tx0 + lx;
    float sv = 0.f;
#pragma unroll
    for (int dy = 0; dy < 3; dy++)
#pragma unroll
      for (int dx = 0; dx < 3; dx++) {
        int y = gy + dy - 1, x = gx + dx - 1;
        if (y >= 0 && y < IMG && x >= 0 && x < IMG) sv += luma[y * IMG + x];
      }
    float cy = 3.f - (gy == 0 ? 1.f : 0.f) - (gy == 63 ? 1.f : 0.f);
    float cx = 3.f - (gx == 0 ? 1.f : 0.f) - (gx == 63 ? 1.f : 0.f);
    float pv = (cy * cx - sv) * (1.f / 9.f);
    pooled[p] = pv;
    red[tid] = pv;
    __syncthreads();
    for (int st = 128; st > 0; st >>= 1) {
      if (tid < st) red[tid] += red[tid + st];
      __syncthreads();
    }
    if (tid == 0) bsums[tile] = red[0];
  }
}

// ---------------------------------------------------------------------------
// gam+bet in one launch: blockIdx.y<4 -> gam, else bet. K=32.
__global__ __launch_bounds__(256) void gemm_gb_kernel(
    const float* __restrict__ Wg, const float* __restrict__ Wb,
    const float* __restrict__ X, const float* __restrict__ bg,
    const float* __restrict__ bb, float* __restrict__ Cg,
    float* __restrict__ Cb) {
  __shared__ float xs[32][64];
  __shared__ float wsh[32][16];
  int yy = blockIdx.y;
  const float* W = yy < 4 ? Wg : Wb;
  const float* bias = yy < 4 ? bg : bb;
  float* C = yy < 4 ? Cg : Cb;
  int n0 = blockIdx.x * 64, m0 = (yy & 3) * 16;
  int tid = threadIdx.x;
  int m = tid >> 4, ng = tid & 15;
  float acc[4] = {};
  {
    int i0 = tid * 2;
    int k = i0 >> 4, nf = (i0 & 15) * 4;
    *(float4*)&xs[k][nf] = *(const float4*)&X[k * NPIX + n0 + nf];
    int i1 = i0 + 1;
    int k1 = i1 >> 4, nf1 = (i1 & 15) * 4;
    *(float4*)&xs[k1][nf1] = *(const float4*)&X[k1 * NPIX + n0 + nf1];
  }
#pragma unroll
  for (int e = tid; e < 512; e += 256) {
    int mm = e >> 5, kk = e & 31;
    wsh[kk][mm] = W[(m0 + mm) * 32 + kk];
  }
  __syncthreads();
#pragma unroll 8
  for (int kk = 0; kk < 32; kk++) {
    float a = wsh[kk][m];
    float4 b4 = *(const float4*)&xs[kk][ng * 4];
    acc[0] = fmaf(a, b4.x, acc[0]);
    acc[1] = fmaf(a, b4.y, acc[1]);
    acc[2] = fmaf(a, b4.z, acc[2]);
    acc[3] = fmaf(a, b4.w, acc[3]);
  }
  int row = m0 + m;
  float bv = bias[row];
  float4 o = make_float4(acc[0] + bv, acc[1] + bv, acc[2] + bv, acc[3] + bv);
  *(float4*)&C[row * NPIX + n0 + ng * 4] = o;
}

// ---------------------------------------------------------------------------
// Fused per-pixel LayerNorm + qkv 1x1 GEMM + modulation + hi/lo split store.
// grid (64 n-blocks, 3 parts). part 0->q, 1->k, 2->v.
// v stored in PV-interleaved layout: vthx[c][jt*32 + g*8 + tau*4 + kk],
// j = jt*32 + tau*16 + g*4 + kk  (matches attn's k-slot assignment).
__global__ __launch_bounds__(256) void ln_qkv_kernel(
    const float* __restrict__ X, const float* __restrict__ lnw,
    const float* __restrict__ lnb, const float* __restrict__ W,
    const float* __restrict__ bias, const float* __restrict__ gmod,
    const float* __restrict__ bmod, const float* __restrict__ pooled,
    const float* __restrict__ bsums, const float* __restrict__ alpha,
    unsigned short* __restrict__ qhl, unsigned short* __restrict__ khl,
    unsigned short* __restrict__ vthx, unsigned short* __restrict__ vtlx) {
  const float QSCALE = 0.35355339059327376f * 1.4426950408889634f;
  __shared__ float xs[64][64];
  __shared__ float wsh[64][64];
  __shared__ float psum[4][64];
  __shared__ float mu[64];
  __shared__ float rs[64];
  int n0 = blockIdx.x * 64, m0 = blockIdx.y * 64;
  int part = blockIdx.y;
  int tid = threadIdx.x;
  int c = tid >> 2, pg = (tid & 3) * 16;
  {
    const float4* src = (const float4*)&X[c * NPIX + n0 + pg];
    float4* dst = (float4*)&xs[c][pg];
    dst[0] = src[0]; dst[1] = src[1]; dst[2] = src[2]; dst[3] = src[3];
  }
  {
    int m = tid >> 2, kg = (tid & 3) * 16;
    const float4* wr = (const float4*)&W[(m0 + m) * 64 + kg];
    float4 w0 = wr[0], w1 = wr[1], w2 = wr[2], w3 = wr[3];
    float wv[16] = {w0.x, w0.y, w0.z, w0.w, w1.x, w1.y, w1.z, w1.w,
                    w2.x, w2.y, w2.z, w2.w, w3.x, w3.y, w3.z, w3.w};
#pragma unroll
    for (int j = 0; j < 16; j++) wsh[kg + j][m] = wv[j];
  }
  __syncthreads();
  int px = tid & 63, qq = tid >> 6;
  float s = 0.f;
#pragma unroll
  for (int cc = 0; cc < 16; cc++) s += xs[qq * 16 + cc][px];
  psum[qq][px] = s;
  __syncthreads();
  if (tid < 64) {
    float t = psum[0][tid] + psum[1][tid] + psum[2][tid] + psum[3][tid];
    mu[tid] = t * (1.f / 64.f);
  }
  __syncthreads();
  float mm = mu[px];
  s = 0.f;
#pragma unroll
  for (int cc = 0; cc < 16; cc++) {
    float d = xs[qq * 16 + cc][px] - mm;
    s = fmaf(d, d, s);
  }
  psum[qq][px] = s;
  __syncthreads();
  if (tid < 64) {
    float t = psum[0][tid] + psum[1][tid] + psum[2][tid] + psum[3][tid];
    rs[tid] = rsqrtf(t * (1.f / 64.f) + 1e-5f);
  }
  __syncthreads();
  {
    float wc = lnw[c], bc = lnb[c];
#pragma unroll
    for (int j = 0; j < 16; j++) {
      int p = pg + j;
      xs[c][p] = (xs[c][p] - mu[p]) * rs[p] * wc + bc;
    }
  }
  __syncthreads();
  int tx = tid & 15, ty = tid >> 4;
  float acc[4][4] = {};
#pragma unroll 8
  for (int kk = 0; kk < 64; kk++) {
    float4 a = *(const float4*)&wsh[kk][ty * 4];
    float4 b4 = *(const float4*)&xs[kk][tx * 4];
    float av[4] = {a.x, a.y, a.z, a.w};
    float bv[4] = {b4.x, b4.y, b4.z, b4.w};
#pragma unroll
    for (int im = 0; im < 4; im++)
#pragma unroll
      for (int in = 0; in < 4; in++)
        acc[im][in] = fmaf(av[im], bv[in], acc[im][in]);
  }
  // epilogue: bias + modulation (+ q extras), hi/lo split, store
  float val[4][4];
#pragma unroll
  for (int im = 0; im < 4; im++) {
    int cc = ty * 4 + im;
    float bv = bias[m0 + cc];
    const float4 gv = *(const float4*)&gmod[cc * NPIX + n0 + tx * 4];
    const float4 bm = *(const float4*)&bmod[cc * NPIX + n0 + tx * 4];
    float ga[4] = {gv.x, gv.y, gv.z, gv.w};
    float ba[4] = {bm.x, bm.y, bm.z, bm.w};
#pragma unroll
    for (int in = 0; in < 4; in++)
      val[im][in] = fmaf(ga[in], acc[im][in] + bv, ba[in]);
  }
  if (part == 0) {
    float msum = 0.f;
#pragma unroll
    for (int t = 0; t < 16; t++) msum += bsums[t];
    float mean = msum * (1.f / 4096.f);
    float a0 = alpha[0];
    const float4 pv = *(const float4*)&pooled[n0 + tx * 4];
    float iv[4] = {a0 * (pv.x - mean), a0 * (pv.y - mean),
                   a0 * (pv.z - mean), a0 * (pv.w - mean)};
#pragma unroll
    for (int im = 0; im < 4; im++)
#pragma unroll
      for (int in = 0; in < 4; in++)
        val[im][in] = (val[im][in] + iv[in]) * QSCALE;
  }
  if (part < 2) {
    unsigned short* dst = (part == 0) ? qhl : khl;
    int h = ty >> 1, d0 = (ty & 1) * 4;
#pragma unroll
    for (int in = 0; in < 4; in++) {
      int n = n0 + tx * 4 + in;
      unsigned int pk[4];
#pragma unroll
      for (int im = 0; im < 4; im++) pk[im] = split_pack(val[im][in]);
      short4 hi, lo;
      hi.x = (short)(pk[0] & 0xffffu); hi.y = (short)(pk[1] & 0xffffu);
      hi.z = (short)(pk[2] & 0xffffu); hi.w = (short)(pk[3] & 0xffffu);
      lo.x = (short)(pk[0] >> 16); lo.y = (short)(pk[1] >> 16);
      lo.z = (short)(pk[2] >> 16); lo.w = (short)(pk[3] >> 16);
      unsigned short* base = dst + ((size_t)(h * NPIX + n) << 4) + d0;
      *(short4*)base = hi;
      *(short4*)(base + 8) = lo;
    }
  } else {
    int nq = n0 + tx * 4;
    int off0 = (nq >> 5) * 32 + ((nq >> 4) & 1) * 4 + ((nq >> 2) & 3) * 8;
#pragma unroll
    for (int im = 0; im < 4; im++) {
      int cc = ty * 4 + im;
      unsigned int pk[4];
#pragma unroll
      for (int in = 0; in < 4; in++) pk[in] = split_pack(val[im][in]);
      short4 hi, lo;
      hi.x = (short)(pk[0] & 0xffffu); hi.y = (short)(pk[1] & 0xffffu);
      hi.z = (short)(pk[2] & 0xffffu); hi.w = (short)(pk[3] & 0xffffu);
      lo.x = (short)(pk[0] >> 16); lo.y = (short)(pk[1] >> 16);
      lo.z = (short)(pk[2] >> 16); lo.w = (short)(pk[3] >> 16);
      *(short4*)(vthx + (size_t)cc * NPIX + off0) = hi;
      *(short4*)(vtlx + (size_t)cc * NPIX + off0) = lo;
    }
  }
}

// ---------------------------------------------------------------------------
// MFMA flash attention, S^T form, ZERO LDS. grid (64 i-tiles, 8 heads, 4 jp).
// S^T = K x Q^T exact via hi/lo K-slot packing. The exp-ed S^T registers ARE
// the PV B-operand under the k-slot assignment jj<4 -> j=4g+jj (tile 0),
// jj>=4 -> j=16+4g+jj-4 (tile 1); V^T pre-stored interleaved to match.
__global__ __launch_bounds__(256, 8) void attn_kernel(
    const unsigned short* __restrict__ qhl,
    const unsigned short* __restrict__ khl,
    const unsigned short* __restrict__ vthx,
    const unsigned short* __restrict__ vtlx, float* __restrict__ pacc,
    float* __restrict__ pml) {
  int tid = threadIdx.x;
  int wave = tid >> 6, lane = tid & 63;
  int g = lane >> 4, c = lane & 15;
  int h = blockIdx.y, jp = blockIdx.z;
  int i0 = blockIdx.x * 64 + wave * 16;
  int jbase = jp * 1024;
  const bf16x8 qB = *(const bf16x8*)(qhl + ((size_t)(h * NPIX + i0 + c) << 4) +
                                     ((g & 1) << 3));
  const unsigned short* kp =
      khl + ((size_t)(h * NPIX + jbase + c) << 4) + ((g >> 1) << 3);
  int dd = c & 7;
  const unsigned short* vhp =
      vthx + (size_t)(h * 8 + dd) * NPIX + jbase + (g << 3);
  const unsigned short* vlp =
      vtlx + (size_t)(h * 8 + dd) * NPIX + jbase + (g << 3);
  floatx4 zero4 = {0.f, 0.f, 0.f, 0.f};
  floatx4 accH = zero4, accM = zero4;
  float m = -INFINITY, l = 0.f;
  for (int jt = 0; jt < 32; ++jt) {
    bf16x8 ka0 = *(const bf16x8*)kp;
    bf16x8 ka1 = *(const bf16x8*)(kp + 256);
    bf16x8 avh = *(const bf16x8*)vhp;
    bf16x8 avl = *(const bf16x8*)vlp;
    kp += 512;
    vhp += 32;
    vlp += 32;
    floatx4 s0 =
        __builtin_amdgcn_mfma_f32_16x16x32_bf16(ka0, qB, zero4, 0, 0, 0);
    floatx4 s1 =
        __builtin_amdgcn_mfma_f32_16x16x32_bf16(ka1, qB, zero4, 0, 0, 0);
    float cm = fmaxf(fmaxf(fmaxf(s0[0], s0[1]), fmaxf(s0[2], s0[3])),
                     fmaxf(fmaxf(s1[0], s1[1]), fmaxf(s1[2], s1[3])));
    cm = fmaxf(cm, __shfl_xor(cm, 16));
    cm = fmaxf(cm, __shfl_xor(cm, 32));
    float mn = fmaxf(m, cm);
    float co = __builtin_amdgcn_exp2f(m - mn);
    m = mn;
    l *= co;
    accH *= co;
    accM *= co;
    float p00 = __builtin_amdgcn_exp2f(s0[0] - mn);
    float p01 = __builtin_amdgcn_exp2f(s0[1] - mn);
    float p02 = __builtin_amdgcn_exp2f(s0[2] - mn);
    float p03 = __builtin_amdgcn_exp2f(s0[3] - mn);
    float p10 = __builtin_amdgcn_exp2f(s1[0] - mn);
    float p11 = __builtin_amdgcn_exp2f(s1[1] - mn);
    float p12 = __builtin_amdgcn_exp2f(s1[2] - mn);
    float p13 = __builtin_amdgcn_exp2f(s1[3] - mn);
    l += ((p00 + p01) + (p02 + p03)) + ((p10 + p11) + (p12 + p13));
    // B-frag hi: dwords (p00,p01)(p02,p03)(p10,p11)(p12,p13), bf16 hi parts
    uintx4 bh;
    bh.x = hi_pair(p00, p01);
    bh.y = hi_pair(p02, p03);
    bh.z = hi_pair(p10, p11);
    bh.w = hi_pair(p12, p13);
    // lo residuals
    float q00 = p00 - __uint_as_float(__float_as_uint(p00) & 0xffff0000u);
    float q01 = p01 - __uint_as_float(__float_as_uint(p01) & 0xffff0000u);
    float q02 = p02 - __uint_as_float(__float_as_uint(p02) & 0xffff0000u);
    float q03 = p03 - __uint_as_float(__float_as_uint(p03) & 0xffff0000u);
    float q10 = p10 - __uint_as_float(__float_as_uint(p10) & 0xffff0000u);
    float q11 = p11 - __uint_as_float(__float_as_uint(p11) & 0xffff0000u);
    float q12 = p12 - __uint_as_float(__float_as_uint(p12) & 0xffff0000u);
    float q13 = p13 - __uint_as_float(__float_as_uint(p13) & 0xffff0000u);
    uintx4 bl;
    bl.x = hi_pair(q00, q01);
    bl.y = hi_pair(q02, q03);
    bl.z = hi_pair(q10, q11);
    bl.w = hi_pair(q12, q13);
    bf16x8 pbh = __builtin_bit_cast(bf16x8, bh);
    bf16x8 pbl = __builtin_bit_cast(bf16x8, bl);
    accH = __builtin_amdgcn_mfma_f32_16x16x32_bf16(avh, pbh, accH, 0, 0, 0);
    accM = __builtin_amdgcn_mfma_f32_16x16x32_bf16(avl, pbh, accM, 0, 0, 0);
    accM = __builtin_amdgcn_mfma_f32_16x16x32_bf16(avh, pbl, accM, 0, 0, 0);
  }
  l += __shfl_xor(l, 16);
  l += __shfl_xor(l, 32);
  floatx4 o = accH + accM;
  if (g < 2) {
    size_t base = (size_t)((jp * 8 + h) * NPIX + i0 + c);
    *(float4*)&pacc[base * 8 + g * 4] = make_float4(o[0], o[1], o[2], o[3]);
    if (g == 0) *(float2*)&pml[base * 2] = make_float2(m, l);
  }
}

// ---------------------------------------------------------------------------
// Fused: combine 4 j-partitions -> attno tile (LDS) -> proj GEMM + bias +
// residual x -> x1, plus per-pixel LN2 stats (mu2, rs2). grid: 128 n-tiles.
__global__ __launch_bounds__(256) void proj_fused_kernel(
    const float* __restrict__ pacc, const float* __restrict__ pml,
    const float* __restrict__ W, const float* __restrict__ bias,
    const float* __restrict__ x, float* __restrict__ x1,
    float* __restrict__ mu2, float* __restrict__ rs2) {
  __shared__ float at[64][36];
  __shared__ float wsh[64][64];
  __shared__ float ps[32][33];
  __shared__ float pq[32][33];
  int n0 = blockIdx.x * 32;
  int tid = threadIdx.x;
  {
    int mm = tid >> 2, kg = (tid & 3) * 16;
    const float4* wr = (const float4*)&W[mm * 64 + kg];
    float4 w0 = wr[0], w1 = wr[1], w2 = wr[2], w3 = wr[3];
    float wv[16] = {w0.x, w0.y, w0.z, w0.w, w1.x, w1.y, w1.z, w1.w,
                    w2.x, w2.y, w2.z, w2.w, w3.x, w3.y, w3.z, w3.w};
#pragma unroll
    for (int j = 0; j < 16; j++) wsh[kg + j][mm] = wv[j];
  }
  {
    int h = tid >> 5, nn = tid & 31;
    int i = n0 + nn;
    float2 ml[4];
#pragma unroll
    for (int p = 0; p < 4; p++)
      ml[p] = *(const float2*)&pml[(size_t)((p * 8 + h) * NPIX + i) * 2];
    float M = fmaxf(fmaxf(ml[0].x, ml[1].x), fmaxf(ml[2].x, ml[3].x));
    float cp[4], L = 0.f;
#pragma unroll
    for (int p = 0; p < 4; p++) {
      cp[p] = __builtin_amdgcn_exp2f(ml[p].x - M);
      L = fmaf(ml[p].y, cp[p], L);
    }
    float inv = 1.f / L;
    float o[8] = {};
#pragma unroll
    for (int p = 0; p < 4; p++) {
      size_t b = (size_t)((p * 8 + h) * NPIX + i) * 8;
      const float4 a0 = *(const float4*)&pacc[b];
      const float4 a1 = *(const float4*)&pacc[b + 4];
      float cc = cp[p];
      o[0] = fmaf(a0.x, cc, o[0]); o[1] = fmaf(a0.y, cc, o[1]);
      o[2] = fmaf(a0.z, cc, o[2]); o[3] = fmaf(a0.w, cc, o[3]);
      o[4] = fmaf(a1.x, cc, o[4]); o[5] = fmaf(a1.y, cc, o[5]);
      o[6] = fmaf(a1.z, cc, o[6]); o[7] = fmaf(a1.w, cc, o[7]);
    }
#pragma unroll
    for (int d = 0; d < 8; d++) at[h * 8 + d][nn] = o[d] * inv;
  }
  __syncthreads();
  int tx = tid & 7, ty = tid >> 3;  // m = 2*ty, n = 4*tx
  float acc[2][4] = {};
#pragma unroll 8
  for (int k = 0; k < 64; k++) {
    float2 a = *(const float2*)&wsh[k][ty * 2];
    float4 b4 = *(const float4*)&at[k][tx * 4];
    acc[0][0] = fmaf(a.x, b4.x, acc[0][0]);
    acc[0][1] = fmaf(a.x, b4.y, acc[0][1]);
    acc[0][2] = fmaf(a.x, b4.z, acc[0][2]);
    acc[0][3] = fmaf(a.x, b4.w, acc[0][3]);
    acc[1][0] = fmaf(a.y, b4.x, acc[1][0]);
    acc[1][1] = fmaf(a.y, b4.y, acc[1][1]);
    acc[1][2] = fmaf(a.y, b4.z, acc[1][2]);
    acc[1][3] = fmaf(a.y, b4.w, acc[1][3]);
  }
  float sn[4] = {0.f, 0.f, 0.f, 0.f}, qn[4] = {0.f, 0.f, 0.f, 0.f};
#pragma unroll
  for (int im = 0; im < 2; im++) {
    int row = ty * 2 + im;
    float bv = bias[row];
    const float4 xv = *(const float4*)&x[row * NPIX + n0 + tx * 4];
    float4 v;
    v.x = acc[im][0] + bv + xv.x;
    v.y = acc[im][1] + bv + xv.y;
    v.z = acc[im][2] + bv + xv.z;
    v.w = acc[im][3] + bv + xv.w;
    *(float4*)&x1[row * NPIX + n0 + tx * 4] = v;
    sn[0] += v.x; sn[1] += v.y; sn[2] += v.z; sn[3] += v.w;
    qn[0] = fmaf(v.x, v.x, qn[0]); qn[1] = fmaf(v.y, v.y, qn[1]);
    qn[2] = fmaf(v.z, v.z, qn[2]); qn[3] = fmaf(v.w, v.w, qn[3]);
  }
#pragma unroll
  for (int in = 0; in < 4; in++) {
    ps[ty][tx * 4 + in] = sn[in];
    pq[ty][tx * 4 + in] = qn[in];
  }
  __syncthreads();
  if (tid < 32) {
    float s = 0.f, q = 0.f;
    for (int t = 0; t < 32; t++) {
      s += ps[t][tid];
      q += pq[t][tid];
    }
    float mu = s * (1.f / 64.f);
    float var = q * (1.f / 64.f) - mu * mu;
    mu2[n0 + tid] = mu;
    rs2[n0 + tid] = rsqrtf(var + 1e-5f);
  }
}

// ---------------------------------------------------------------------------
// ffn1: LN (precomputed stats) applied during staging + 1x1 GEMM.
__global__ __launch_bounds__(256) void ffn1_kernel(
    const float* __restrict__ X, const float* __restrict__ mu2,
    const float* __restrict__ rs2, const float* __restrict__ lnw,
    const float* __restrict__ lnb, const float* __restrict__ W,
    const float* __restrict__ bias, float* __restrict__ C) {
  __shared__ float xs[64][64];
  __shared__ float wsh[64][64];
  int n0 = blockIdx.x * 64, m0 = blockIdx.y * 64;
  int tid = threadIdx.x;
  int c = tid >> 2, pg = (tid & 3) * 16;
  {
    float wc = lnw[c], bc = lnb[c];
    const float4* src = (const float4*)&X[c * NPIX + n0 + pg];
    const float4* mup = (const float4*)&mu2[n0 + pg];
    const float4* rsp = (const float4*)&rs2[n0 + pg];
#pragma unroll
    for (int j4 = 0; j4 < 4; j4++) {
      float4 xv = src[j4], mv = mup[j4], rv = rsp[j4];
      float4 o;
      o.x = (xv.x - mv.x) * rv.x * wc + bc;
      o.y = (xv.y - mv.y) * rv.y * wc + bc;
      o.z = (xv.z - mv.z) * rv.z * wc + bc;
      o.w = (xv.w - mv.w) * rv.w * wc + bc;
      *(float4*)&xs[c][pg + j4 * 4] = o;
    }
  }
  {
    int m = tid >> 2, kg = (tid & 3) * 16;
    const float4* wr = (const float4*)&W[(m0 + m) * 64 + kg];
    float4 w0 = wr[0], w1 = wr[1], w2 = wr[2], w3 = wr[3];
    float wv[16] = {w0.x, w0.y, w0.z, w0.w, w1.x, w1.y, w1.z, w1.w,
                    w2.x, w2.y, w2.z, w2.w, w3.x, w3.y, w3.z, w3.w};
#pragma unroll
    for (int j = 0; j < 16; j++) wsh[kg + j][m] = wv[j];
  }
  __syncthreads();
  int tx = tid & 15, ty = tid >> 4;
  float acc[4][4] = {};
#pragma unroll 8
  for (int kk = 0; kk < 64; kk++) {
    float4 a = *(const float4*)&wsh[kk][ty * 4];
    float4 b4 = *(const float4*)&xs[kk][tx * 4];
    float av[4] = {a.x, a.y, a.z, a.w};
    float bv[4] = {b4.x, b4.y, b4.z, b4.w};
#pragma unroll
    for (int im = 0; im < 4; im++)
#pragma unroll
      for (int in = 0; in < 4; in++)
        acc[im][in] = fmaf(av[im], bv[in], acc[im][in]);
  }
#pragma unroll
  for (int im = 0; im < 4; im++) {
    int mrow = m0 + ty * 4 + im;
    float bv = bias[mrow];
    float4 o = make_float4(acc[im][0] + bv, acc[im][1] + bv, acc[im][2] + bv,
                           acc[im][3] + bv);
    *(float4*)&C[mrow * NPIX + n0 + tx * 4] = o;
  }
}

// ---------------------------------------------------------------------------
// Thin GEMM, 16m x 32n tiles: C = W[M][K]*X + bias (+resid). grid (128, M/16).
__global__ __launch_bounds__(256) void gemm16_kernel(
    const float* __restrict__ W, const float* __restrict__ X,
    const float* __restrict__ bias, const float* __restrict__ resid,
    float* __restrict__ C, int K) {
  __shared__ float xs[32][32];
  __shared__ float wsh[32][16];
  int n0 = blockIdx.x * 32, m0 = blockIdx.y * 16;
  int tid = threadIdx.x;
  int m = tid >> 4, np = (tid & 15) * 2;
  float acc0 = 0.f, acc1 = 0.f;
  for (int k0 = 0; k0 < K; k0 += 32) {
    {
      int k = tid >> 3, nf = (tid & 7) * 4;
      *(float4*)&xs[k][nf] = *(const float4*)&X[(k0 + k) * NPIX + n0 + nf];
    }
#pragma unroll
    for (int e = tid; e < 512; e += 256) {
      int kk = e >> 4, mm = e & 15;
      wsh[kk][mm] = W[(m0 + mm) * K + k0 + kk];
    }
    __syncthreads();
#pragma unroll 8
    for (int kk = 0; kk < 32; kk++) {
      float a = wsh[kk][m];
      float2 b2 = *(const float2*)&xs[kk][np];
      acc0 = fmaf(a, b2.x, acc0);
      acc1 = fmaf(a, b2.y, acc1);
    }
    __syncthreads();
  }
  int row = m0 + m;
  float bv = bias[row];
  float2 o = make_float2(acc0 + bv, acc1 + bv);
  if (resid) {
    const float2 r2 = *(const float2*)&resid[row * NPIX + n0 + np];
    o.x += r2.x;
    o.y += r2.y;
  }
  *(float2*)&C[row * NPIX + n0 + np] = o;
}

// ---------------------------------------------------------------------------
// Depthwise 3x3 + exact GELU; 4 horizontal px/thread.
__global__ __launch_bounds__(256) void dw_gelu_kernel(
    const float* __restrict__ f1, const float* __restrict__ w,
    const float* __restrict__ b, float* __restrict__ f2) {
  int t = blockIdx.x * 256 + threadIdx.x;
  int c = t >> 10, pq = t & 1023;
  int py = pq >> 4, px0 = (pq & 15) << 2;
  const float* base = f1 + c * NPIX;
  float wv[9];
#pragma unroll
  for (int i = 0; i < 9; i++) wv[i] = w[c * 9 + i];
  float bc = b[c];
  float a[4] = {bc, bc, bc, bc};
#pragma unroll
  for (int dy = 0; dy < 3; dy++) {
    int y = py + dy - 1;
    if (y < 0 || y > 63) continue;
    const float* row = base + y * IMG + px0;
    float4 mid = *(const float4*)row;
    float left = (px0 > 0) ? row[-1] : 0.f;
    float right = (px0 < 60) ? row[4] : 0.f;
    float win[6] = {left, mid.x, mid.y, mid.z, mid.w, right};
#pragma unroll
    for (int o = 0; o < 4; o++)
#pragma unroll
      for (int dx = 0; dx < 3; dx++)
        a[o] = fmaf(wv[dy * 3 + dx], win[o + dx], a[o]);
  }
  float4 o4;
  float* op = &o4.x;
#pragma unroll
  for (int o = 0; o < 4; o++)
    op[o] = 0.5f * a[o] * (1.f + erff(a[o] * 0.70710678118654752f));
  *(float4*)&f2[c * NPIX + py * IMG + px0] = o4;
}

// ---------------------------------------------------------------------------
extern "C" void kernel_launch(void* const* d_in, const int* in_sizes, int n_in,
                              void* d_out, int out_size, void* d_ws,
                              size_t ws_size, hipStream_t stream) {
  const float* x      = (const float*)d_in[0];
  const float* luma   = (const float*)d_in[1];
  const float* ln1_w  = (const float*)d_in[2];
  const float* ln1_b  = (const float*)d_in[3];
  const float* qkv_w  = (const float*)d_in[4];
  const float* qkv_b  = (const float*)d_in[5];
  const float* proj_w = (const float*)d_in[6];
  const float* proj_b = (const float*)d_in[7];
  const float* lc1_w  = (const float*)d_in[8];
  const float* lc1_b  = (const float*)d_in[9];
  const float* lc2_w  = (const float*)d_in[10];
  const float* lc2_b  = (const float*)d_in[11];
  const float* gam_w  = (const float*)d_in[12];
  const float* gam_b  = (const float*)d_in[13];
  const float* bet_w  = (const float*)d_in[14];
  const float* bet_b  = (const float*)d_in[15];
  const float* alpha  = (const float*)d_in[16];
  const float* ln2_w  = (const float*)d_in[17];
  const float* ln2_b  = (const float*)d_in[18];
  const float* ffn1_w = (const float*)d_in[19];
  const float* ffn1_b = (const float*)d_in[20];
  const float* dw_w   = (const float*)d_in[21];
  const float* dw_b   = (const float*)d_in[22];
  const float* ffn2_w = (const float*)d_in[23];
  const float* ffn2_b = (const float*)d_in[24];
  float* out = (float*)d_out;

  float* w = (float*)d_ws;
  float* pooled = w + 0;        // 4096
  float* bsums  = w + 4096;     // 64 (16 used)
  unsigned short* qhl  = (unsigned short*)(w + 4160);     // 262144 f
  unsigned short* khl  = (unsigned short*)(w + 266304);   // 262144 f
  unsigned short* vthx = (unsigned short*)(w + 528448);   // 131072 f
  unsigned short* vtlx = (unsigned short*)(w + 659520);   // 131072 f
  float* pacc = w + 790592;    // 1048576
  float* pml  = w + 1839168;   // 262144
  float* x1   = w + 2101312;   // 262144
  float* mu2  = w + 2363456;   // 4096
  float* rs2  = w + 2367552;   // 4096
  float* f1   = w + 2371648;   // 1048576
  float* f2   = w + 3420224;   // 1048576
  float* h2   = w + 4468800;   // 131072
  float* g    = w + 4599872;   // 262144
  float* bt   = w + 4862016;   // 262144

  lc_fused_kernel<<<dim3(16, 8), 256, 0, stream>>>(luma, lc1_w, lc1_b, lc2_w,
                                                   lc2_b, h2, pooled, bsums);
  gemm_gb_kernel<<<dim3(64, 8), 256, 0, stream>>>(gam_w, bet_w, h2, gam_b,
                                                  bet_b, g, bt);
  ln_qkv_kernel<<<dim3(64, 3), 256, 0, stream>>>(x, ln1_w, ln1_b, qkv_w, qkv_b,
                                                 g, bt, pooled, bsums, alpha,
                                                 qhl, khl, vthx, vtlx);
  attn_kernel<<<dim3(64, 8, 4), 256, 0, stream>>>(qhl, khl, vthx, vtlx, pacc,
                                                  pml);
  proj_fused_kernel<<<128, 256, 0, stream>>>(pacc, pml, proj_w, proj_b, x, x1,
                                             mu2, rs2);
  ffn1_kernel<<<dim3(64, 4), 256, 0, stream>>>(x1, mu2, rs2, ln2_w, ln2_b,
                                               ffn1_w, ffn1_b, f1);
  dw_gelu_kernel<<<1024, 256, 0, stream>>>(f1, dw_w, dw_b, f2);
  gemm16_kernel<<<dim3(128, 4), 256, 0, stream>>>(ffn2_w, f2, ffn2_b, x1, out,
                                                  256);
}

// Round 6
// 240.631 us; speedup vs baseline: 1.2356x; 1.1023x over previous
//
#include <hip/hip_runtime.h>
#include <math.h>

// B=1, C=64, H=W=64, N=4096, heads=8, dh=8, inner=64, hid_lc=32, hid_f=256.
#define NPIX 4096
#define IMG 64

typedef __attribute__((ext_vector_type(8))) short bf16x8;
typedef __attribute__((ext_vector_type(4))) float floatx4;
typedef __attribute__((ext_vector_type(4))) unsigned int uintx4;

// fp32 -> (hi bf16 in low16) | (lo bf16 in high16), lo = x - f32(hi)
__device__ __forceinline__ unsigned int split_pack(float x) {
  unsigned int u = __float_as_uint(x);
  unsigned int hif = u & 0xffff0000u;
  float lof = x - __uint_as_float(hif);
  return (u >> 16) | (__float_as_uint(lof) & 0xffff0000u);
}

// pack hi16 of two floats: low16 = hi16(a), high16 = hi16(b)
__device__ __forceinline__ unsigned int hi_pair(float a, float b) {
  return (__float_as_uint(a) >> 16) | (__float_as_uint(b) & 0xffff0000u);
}

// ---------------------------------------------------------------------------
// Fused luma branch: recompute h1=relu(conv3x3(luma)) per-tile (halo), then
// lc2 conv -> h2. ocg==0 blocks also emit pooled + per-tile partial sums.
// Block (0,0) also initializes the attn constant buffer (ones/zeros bf16).
__global__ __launch_bounds__(256) void lc_fused_kernel(
    const float* __restrict__ luma, const float* __restrict__ w1,
    const float* __restrict__ b1, const float* __restrict__ w2,
    const float* __restrict__ b2, float* __restrict__ h2,
    float* __restrict__ pooled, float* __restrict__ bsums,
    unsigned short* __restrict__ cbuf) {
  __shared__ float tin[32][324];  // h1 on 18x18 halo per ic
  __shared__ float swt[4][32][9];
  __shared__ float red[256];
  int tile = blockIdx.x, ocg = blockIdx.y;
  int ty0 = (tile >> 2) * 16, tx0 = (tile & 3) * 16;
  int tid = threadIdx.x;
  if (tile == 0 && ocg == 0 && tid < 16) cbuf[tid] = (tid < 8) ? 0x3F80 : 0;
  for (int idx = tid; idx < 32 * 324; idx += 256) {
    int ic = idx / 324, pos = idx - ic * 324;
    int py = pos / 18, px = pos - py * 18;
    int gy = ty0 + py - 1, gx = tx0 + px - 1;
    float v = 0.f;
    if (gy >= 0 && gy < IMG && gx >= 0 && gx < IMG) {
      float s = b1[ic];
#pragma unroll
      for (int dy = 0; dy < 3; dy++)
#pragma unroll
        for (int dx = 0; dx < 3; dx++) {
          int y = gy + dy - 1, x = gx + dx - 1;
          if (y >= 0 && y < IMG && x >= 0 && x < IMG)
            s = fmaf(w1[ic * 9 + dy * 3 + dx], luma[y * IMG + x], s);
        }
      v = fmaxf(s, 0.f);
    }
    tin[ic][pos] = v;
  }
  for (int idx = tid; idx < 4 * 32 * 9; idx += 256) {
    int o = idx / 288, r = idx - o * 288;
    swt[o][r / 9][r % 9] = w2[(ocg * 4 + o) * 288 + r];
  }
  __syncthreads();
  int ly = tid >> 4, lx = tid & 15;
  int p = (ty0 + ly) * IMG + tx0 + lx;
  float acc[4];
#pragma unroll
  for (int o = 0; o < 4; o++) acc[o] = b2[ocg * 4 + o];
  for (int ic = 0; ic < 32; ic++) {
    float v[9];
#pragma unroll
    for (int dy = 0; dy < 3; dy++)
#pragma unroll
      for (int dx = 0; dx < 3; dx++)
        v[dy * 3 + dx] = tin[ic][(ly + dy) * 18 + lx + dx];
#pragma unroll
    for (int o = 0; o < 4; o++)
#pragma unroll
      for (int t = 0; t < 9; t++) acc[o] = fmaf(swt[o][ic][t], v[t], acc[o]);
  }
#pragma unroll
  for (int o = 0; o < 4; o++)
    h2[(ocg * 4 + o) * NPIX + p] = fmaxf(acc[o], 0.f);
  if (ocg == 0) {
    int gy = ty0 + ly, gx = tx0 + lx;
    float sv = 0.f;
#pragma unroll
    for (int dy = 0; dy < 3; dy++)
#pragma unroll
      for (int dx = 0; dx < 3; dx++) {
        int y = gy + dy - 1, x = gx + dx - 1;
        if (y >= 0 && y < IMG && x >= 0 && x < IMG) sv += luma[y * IMG + x];
      }
    float cy = 3.f - (gy == 0 ? 1.f : 0.f) - (gy == 63 ? 1.f : 0.f);
    float cx = 3.f - (gx == 0 ? 1.f : 0.f) - (gx == 63 ? 1.f : 0.f);
    float pv = (cy * cx - sv) * (1.f / 9.f);
    pooled[p] = pv;
    red[tid] = pv;
    __syncthreads();
    for (int st = 128; st > 0; st >>= 1) {
      if (tid < st) red[tid] += red[tid + st];
      __syncthreads();
    }
    if (tid == 0) bsums[tile] = red[0];
  }
}

// ---------------------------------------------------------------------------
// Fused per-pixel LayerNorm + qkv 1x1 GEMM + (gam/bet GEMMs in-register) +
// modulation + hi/lo split store. grid (64 n-blocks, 3 parts).
__global__ __launch_bounds__(256) void ln_qkv_kernel(
    const float* __restrict__ X, const float* __restrict__ lnw,
    const float* __restrict__ lnb, const float* __restrict__ W,
    const float* __restrict__ bias, const float* __restrict__ gamW,
    const float* __restrict__ gamB, const float* __restrict__ betW,
    const float* __restrict__ betB, const float* __restrict__ h2,
    const float* __restrict__ pooled, const float* __restrict__ bsums,
    const float* __restrict__ alpha, unsigned short* __restrict__ qhl,
    unsigned short* __restrict__ khl, unsigned short* __restrict__ vthx,
    unsigned short* __restrict__ vtlx) {
  const float QSCALE = 0.35355339059327376f * 1.4426950408889634f;
  __shared__ float xs[64][64];
  __shared__ float wsh[64][64];
  __shared__ float h2s[32][64];
  __shared__ float wgs[32][64];
  __shared__ float wbs[32][64];
  __shared__ float psum[4][64];
  __shared__ float mu[64];
  __shared__ float rs[64];
  int n0 = blockIdx.x * 64, part = blockIdx.y, m0 = part * 64;
  int tid = threadIdx.x;
  int c = tid >> 2, pg = (tid & 3) * 16;
  {
    const float4* src = (const float4*)&X[c * NPIX + n0 + pg];
    float4* dst = (float4*)&xs[c][pg];
    dst[0] = src[0]; dst[1] = src[1]; dst[2] = src[2]; dst[3] = src[3];
  }
  {
    int m = tid >> 2, kg = (tid & 3) * 16;
    const float4* wr = (const float4*)&W[(m0 + m) * 64 + kg];
    float4 w0 = wr[0], w1 = wr[1], w2 = wr[2], w3 = wr[3];
    float wv[16] = {w0.x, w0.y, w0.z, w0.w, w1.x, w1.y, w1.z, w1.w,
                    w2.x, w2.y, w2.z, w2.w, w3.x, w3.y, w3.z, w3.w};
#pragma unroll
    for (int j = 0; j < 16; j++) wsh[kg + j][m] = wv[j];
  }
  {
    int i0 = tid * 2;
    int k = i0 >> 4, nf = (i0 & 15) * 4;
    *(float4*)&h2s[k][nf] = *(const float4*)&h2[k * NPIX + n0 + nf];
    int i1 = i0 + 1;
    int k1 = i1 >> 4, nf1 = (i1 & 15) * 4;
    *(float4*)&h2s[k1][nf1] = *(const float4*)&h2[k1 * NPIX + n0 + nf1];
  }
  {
    int m = tid >> 2, kg = (tid & 3) * 8;
    const float4* g0 = (const float4*)&gamW[m * 32 + kg];
    float4 a = g0[0], b4 = g0[1];
    float gv[8] = {a.x, a.y, a.z, a.w, b4.x, b4.y, b4.z, b4.w};
#pragma unroll
    for (int j = 0; j < 8; j++) wgs[kg + j][m] = gv[j];
    const float4* bb0 = (const float4*)&betW[m * 32 + kg];
    float4 c4 = bb0[0], d4 = bb0[1];
    float bv[8] = {c4.x, c4.y, c4.z, c4.w, d4.x, d4.y, d4.z, d4.w};
#pragma unroll
    for (int j = 0; j < 8; j++) wbs[kg + j][m] = bv[j];
  }
  __syncthreads();
  int px = tid & 63, qq = tid >> 6;
  float s = 0.f;
#pragma unroll
  for (int cc = 0; cc < 16; cc++) s += xs[qq * 16 + cc][px];
  psum[qq][px] = s;
  __syncthreads();
  if (tid < 64) {
    float t = psum[0][tid] + psum[1][tid] + psum[2][tid] + psum[3][tid];
    mu[tid] = t * (1.f / 64.f);
  }
  __syncthreads();
  float mm = mu[px];
  s = 0.f;
#pragma unroll
  for (int cc = 0; cc < 16; cc++) {
    float d = xs[qq * 16 + cc][px] - mm;
    s = fmaf(d, d, s);
  }
  psum[qq][px] = s;
  __syncthreads();
  if (tid < 64) {
    float t = psum[0][tid] + psum[1][tid] + psum[2][tid] + psum[3][tid];
    rs[tid] = rsqrtf(t * (1.f / 64.f) + 1e-5f);
  }
  __syncthreads();
  {
    float wc = lnw[c], bc = lnb[c];
#pragma unroll
    for (int j = 0; j < 16; j++) {
      int p = pg + j;
      xs[c][p] = (xs[c][p] - mu[p]) * rs[p] * wc + bc;
    }
  }
  __syncthreads();
  int tx = tid & 15, ty = tid >> 4;
  // gam/bet for this thread's 4 ch x 4 px
  float ga[4][4] = {}, ba[4][4] = {};
#pragma unroll 8
  for (int kk = 0; kk < 32; kk++) {
    float4 wg4 = *(const float4*)&wgs[kk][ty * 4];
    float4 wb4 = *(const float4*)&wbs[kk][ty * 4];
    float4 h24 = *(const float4*)&h2s[kk][tx * 4];
    float gv[4] = {wg4.x, wg4.y, wg4.z, wg4.w};
    float bv[4] = {wb4.x, wb4.y, wb4.z, wb4.w};
    float hv[4] = {h24.x, h24.y, h24.z, h24.w};
#pragma unroll
    for (int im = 0; im < 4; im++)
#pragma unroll
      for (int in = 0; in < 4; in++) {
        ga[im][in] = fmaf(gv[im], hv[in], ga[im][in]);
        ba[im][in] = fmaf(bv[im], hv[in], ba[im][in]);
      }
  }
#pragma unroll
  for (int im = 0; im < 4; im++) {
    int cc = ty * 4 + im;
    float gb = gamB[cc], bb2 = betB[cc];
#pragma unroll
    for (int in = 0; in < 4; in++) {
      ga[im][in] += gb;
      ba[im][in] += bb2;
    }
  }
  // main qkv GEMM
  float acc[4][4] = {};
#pragma unroll 8
  for (int kk = 0; kk < 64; kk++) {
    float4 a = *(const float4*)&wsh[kk][ty * 4];
    float4 b4 = *(const float4*)&xs[kk][tx * 4];
    float av[4] = {a.x, a.y, a.z, a.w};
    float bv[4] = {b4.x, b4.y, b4.z, b4.w};
#pragma unroll
    for (int im = 0; im < 4; im++)
#pragma unroll
      for (int in = 0; in < 4; in++)
        acc[im][in] = fmaf(av[im], bv[in], acc[im][in]);
  }
  // epilogue: bias + modulation (+ q extras), hi/lo split, store
  float val[4][4];
#pragma unroll
  for (int im = 0; im < 4; im++) {
    int cc = ty * 4 + im;
    float bv = bias[m0 + cc];
#pragma unroll
    for (int in = 0; in < 4; in++)
      val[im][in] = fmaf(ga[im][in], acc[im][in] + bv, ba[im][in]);
  }
  if (part == 0) {
    float msum = 0.f;
#pragma unroll
    for (int t = 0; t < 16; t++) msum += bsums[t];
    float mean = msum * (1.f / 4096.f);
    float a0 = alpha[0];
    const float4 pv = *(const float4*)&pooled[n0 + tx * 4];
    float iv[4] = {a0 * (pv.x - mean), a0 * (pv.y - mean),
                   a0 * (pv.z - mean), a0 * (pv.w - mean)};
#pragma unroll
    for (int im = 0; im < 4; im++)
#pragma unroll
      for (int in = 0; in < 4; in++)
        val[im][in] = (val[im][in] + iv[in]) * QSCALE;
  }
  if (part < 2) {
    unsigned short* dst = (part == 0) ? qhl : khl;
    int h = ty >> 1, d0 = (ty & 1) * 4;
#pragma unroll
    for (int in = 0; in < 4; in++) {
      int n = n0 + tx * 4 + in;
      unsigned int pk[4];
#pragma unroll
      for (int im = 0; im < 4; im++) pk[im] = split_pack(val[im][in]);
      short4 hi, lo;
      hi.x = (short)(pk[0] & 0xffffu); hi.y = (short)(pk[1] & 0xffffu);
      hi.z = (short)(pk[2] & 0xffffu); hi.w = (short)(pk[3] & 0xffffu);
      lo.x = (short)(pk[0] >> 16); lo.y = (short)(pk[1] >> 16);
      lo.z = (short)(pk[2] >> 16); lo.w = (short)(pk[3] >> 16);
      unsigned short* base = dst + ((size_t)(h * NPIX + n) << 4) + d0;
      *(short4*)base = hi;
      *(short4*)(base + 8) = lo;
    }
  } else {
    int nq = n0 + tx * 4;
    int off0 = (nq >> 5) * 32 + ((nq >> 4) & 1) * 4 + ((nq >> 2) & 3) * 8;
#pragma unroll
    for (int im = 0; im < 4; im++) {
      int cc = ty * 4 + im;
      unsigned int pk[4];
#pragma unroll
      for (int in = 0; in < 4; in++) pk[in] = split_pack(val[im][in]);
      short4 hi, lo;
      hi.x = (short)(pk[0] & 0xffffu); hi.y = (short)(pk[1] & 0xffffu);
      hi.z = (short)(pk[2] & 0xffffu); hi.w = (short)(pk[3] & 0xffffu);
      lo.x = (short)(pk[0] >> 16); lo.y = (short)(pk[1] >> 16);
      lo.z = (short)(pk[2] >> 16); lo.w = (short)(pk[3] >> 16);
      *(short4*)(vthx + (size_t)cc * NPIX + off0) = hi;
      *(short4*)(vtlx + (size_t)cc * NPIX + off0) = lo;
    }
  }
}

// ---------------------------------------------------------------------------
// MFMA flash attention, S^T form, NO online max (exp2 of raw clamped scores:
// ratio identical to softmax; scores are O(10), clamp at 80 prevents
// overflow: 4096*2^80 << fp32 max). A-row 8 = ones -> PV output row 8 = sum p
// (the softmax denominator) for free. Zero LDS, zero cross-lane ops;
// iterations fully independent -> pipelined. grid (64 i-tiles, 8 h, 4 jp).
__global__ __launch_bounds__(256, 8) void attn_kernel(
    const unsigned short* __restrict__ qhl,
    const unsigned short* __restrict__ khl,
    const unsigned short* __restrict__ vthx,
    const unsigned short* __restrict__ vtlx,
    const unsigned short* __restrict__ cbuf, float* __restrict__ pacc,
    float* __restrict__ pl) {
  int tid = threadIdx.x;
  int wave = tid >> 6, lane = tid & 63;
  int g = lane >> 4, c = lane & 15;
  int h = blockIdx.y, jp = blockIdx.z;
  int i0 = blockIdx.x * 64 + wave * 16;
  int jbase = jp * 1024;
  const bf16x8 qB = *(const bf16x8*)(qhl + ((size_t)(h * NPIX + i0 + c) << 4) +
                                     ((g & 1) << 3));
  const unsigned short* kp =
      khl + ((size_t)(h * NPIX + jbase + c) << 4) + ((g >> 1) << 3);
  const unsigned short* vhp;
  const unsigned short* vlp;
  int vstep;
  if (c < 8) {
    vhp = vthx + (size_t)(h * 8 + c) * NPIX + jbase + (g << 3);
    vlp = vtlx + (size_t)(h * 8 + c) * NPIX + jbase + (g << 3);
    vstep = 32;
  } else {
    vhp = (c == 8) ? cbuf : (cbuf + 8);  // ones row / zero rows
    vlp = cbuf + 8;
    vstep = 0;
  }
  floatx4 zero4 = {0.f, 0.f, 0.f, 0.f};
  floatx4 accH = zero4, accM = zero4;
#pragma unroll 4
  for (int jt = 0; jt < 32; ++jt) {
    bf16x8 ka0 = *(const bf16x8*)kp;
    bf16x8 ka1 = *(const bf16x8*)(kp + 256);
    bf16x8 avh = *(const bf16x8*)vhp;
    bf16x8 avl = *(const bf16x8*)vlp;
    kp += 512;
    vhp += vstep;
    vlp += vstep;
    floatx4 s0 =
        __builtin_amdgcn_mfma_f32_16x16x32_bf16(ka0, qB, zero4, 0, 0, 0);
    floatx4 s1 =
        __builtin_amdgcn_mfma_f32_16x16x32_bf16(ka1, qB, zero4, 0, 0, 0);
    float p00 = __builtin_amdgcn_exp2f(fminf(s0[0], 80.f));
    float p01 = __builtin_amdgcn_exp2f(fminf(s0[1], 80.f));
    float p02 = __builtin_amdgcn_exp2f(fminf(s0[2], 80.f));
    float p03 = __builtin_amdgcn_exp2f(fminf(s0[3], 80.f));
    float p10 = __builtin_amdgcn_exp2f(fminf(s1[0], 80.f));
    float p11 = __builtin_amdgcn_exp2f(fminf(s1[1], 80.f));
    float p12 = __builtin_amdgcn_exp2f(fminf(s1[2], 80.f));
    float p13 = __builtin_amdgcn_exp2f(fminf(s1[3], 80.f));
    uintx4 bh;
    bh.x = hi_pair(p00, p01);
    bh.y = hi_pair(p02, p03);
    bh.z = hi_pair(p10, p11);
    bh.w = hi_pair(p12, p13);
    float q00 = p00 - __uint_as_float(__float_as_uint(p00) & 0xffff0000u);
    float q01 = p01 - __uint_as_float(__float_as_uint(p01) & 0xffff0000u);
    float q02 = p02 - __uint_as_float(__float_as_uint(p02) & 0xffff0000u);
    float q03 = p03 - __uint_as_float(__float_as_uint(p03) & 0xffff0000u);
    float q10 = p10 - __uint_as_float(__float_as_uint(p10) & 0xffff0000u);
    float q11 = p11 - __uint_as_float(__float_as_uint(p11) & 0xffff0000u);
    float q12 = p12 - __uint_as_float(__float_as_uint(p12) & 0xffff0000u);
    float q13 = p13 - __uint_as_float(__float_as_uint(p13) & 0xffff0000u);
    uintx4 bl;
    bl.x = hi_pair(q00, q01);
    bl.y = hi_pair(q02, q03);
    bl.z = hi_pair(q10, q11);
    bl.w = hi_pair(q12, q13);
    bf16x8 pbh = __builtin_bit_cast(bf16x8, bh);
    bf16x8 pbl = __builtin_bit_cast(bf16x8, bl);
    accH = __builtin_amdgcn_mfma_f32_16x16x32_bf16(avh, pbh, accH, 0, 0, 0);
    accM = __builtin_amdgcn_mfma_f32_16x16x32_bf16(avl, pbh, accM, 0, 0, 0);
    accM = __builtin_amdgcn_mfma_f32_16x16x32_bf16(avh, pbl, accM, 0, 0, 0);
  }
  floatx4 o = accH + accM;
  if (g < 2) {
    size_t base = (size_t)((jp * 8 + h) * NPIX + i0 + c);
    *(float4*)&pacc[base * 8 + g * 4] = make_float4(o[0], o[1], o[2], o[3]);
  } else if (g == 2) {
    pl[(size_t)((jp * 8 + h) * NPIX + i0 + c)] = o[0];  // row 8 = sum p
  }
}

// ---------------------------------------------------------------------------
// Fused: combine 4 j-partitions (plain sums, no max) -> proj GEMM + bias +
// residual -> x1 + LN2 stats -> LN apply -> ffn1 GEMM -> f1.
// grid: 256 blocks of 16 px.
__global__ __launch_bounds__(256) void proj_ffn1_kernel(
    const float* __restrict__ pacc, const float* __restrict__ pl,
    const float* __restrict__ Wp, const float* __restrict__ bp,
    const float* __restrict__ x, const float* __restrict__ ln2w,
    const float* __restrict__ ln2b, const float* __restrict__ W1,
    const float* __restrict__ b1f, float* __restrict__ x1,
    float* __restrict__ f1) {
  __shared__ float at[64][17];
  __shared__ float wsh[64][64];
  __shared__ float xsl[64][17];
  __shared__ float ps[16][17];
  __shared__ float pq[16][17];
  __shared__ float mus[16];
  __shared__ float rss[16];
  int n0 = blockIdx.x * 16;
  int tid = threadIdx.x;
  int ty = tid >> 4, tx = tid & 15;
  {
    int mm = tid >> 2, kg = (tid & 3) * 16;
    const float4* wr = (const float4*)&Wp[mm * 64 + kg];
    float4 w0 = wr[0], w1 = wr[1], w2 = wr[2], w3 = wr[3];
    float wv[16] = {w0.x, w0.y, w0.z, w0.w, w1.x, w1.y, w1.z, w1.w,
                    w2.x, w2.y, w2.z, w2.w, w3.x, w3.y, w3.z, w3.w};
#pragma unroll
    for (int j = 0; j < 16; j++) wsh[kg + j][mm] = wv[j];
  }
  if (tid < 128) {
    int h = tid >> 4, nn = tid & 15;
    int i = n0 + nn;
    float L = 0.f, o[8] = {};
#pragma unroll
    for (int p = 0; p < 4; p++) {
      size_t base = (size_t)((p * 8 + h) * NPIX + i);
      L += pl[base];
      const float4 a0 = *(const float4*)&pacc[base * 8];
      const float4 a1 = *(const float4*)&pacc[base * 8 + 4];
      o[0] += a0.x; o[1] += a0.y; o[2] += a0.z; o[3] += a0.w;
      o[4] += a1.x; o[5] += a1.y; o[6] += a1.z; o[7] += a1.w;
    }
    float inv = 1.f / L;
#pragma unroll
    for (int d = 0; d < 8; d++) at[h * 8 + d][nn] = o[d] * inv;
  }
  __syncthreads();
  float acc[4] = {};
#pragma unroll 8
  for (int k = 0; k < 64; k++) {
    float4 a4 = *(const float4*)&wsh[k][ty * 4];
    float b = at[k][tx];
    acc[0] = fmaf(a4.x, b, acc[0]);
    acc[1] = fmaf(a4.y, b, acc[1]);
    acc[2] = fmaf(a4.z, b, acc[2]);
    acc[3] = fmaf(a4.w, b, acc[3]);
  }
  float v[4], sn = 0.f, qn = 0.f;
#pragma unroll
  for (int im = 0; im < 4; im++) {
    int row = ty * 4 + im;
    float vv = acc[im] + bp[row] + x[row * NPIX + n0 + tx];
    v[im] = vv;
    x1[row * NPIX + n0 + tx] = vv;
    sn += vv;
    qn = fmaf(vv, vv, qn);
  }
  ps[ty][tx] = sn;
  pq[ty][tx] = qn;
  __syncthreads();
  if (tid < 16) {
    float s = 0.f, q = 0.f;
    for (int t = 0; t < 16; t++) {
      s += ps[t][tid];
      q += pq[t][tid];
    }
    float mu = s * (1.f / 64.f);
    mus[tid] = mu;
    rss[tid] = rsqrtf(q * (1.f / 64.f) - mu * mu + 1e-5f);
  }
  __syncthreads();
  {
    float muv = mus[tx], rsv = rss[tx];
#pragma unroll
    for (int im = 0; im < 4; im++) {
      int row = ty * 4 + im;
      xsl[row][tx] = (v[im] - muv) * rsv * ln2w[row] + ln2b[row];
    }
  }
  for (int ch = 0; ch < 4; ch++) {
    __syncthreads();
    {
      int mm = tid >> 2, kg = (tid & 3) * 16;
      const float4* wr = (const float4*)&W1[(ch * 64 + mm) * 64 + kg];
      float4 w0 = wr[0], w1 = wr[1], w2 = wr[2], w3 = wr[3];
      float wv[16] = {w0.x, w0.y, w0.z, w0.w, w1.x, w1.y, w1.z, w1.w,
                      w2.x, w2.y, w2.z, w2.w, w3.x, w3.y, w3.z, w3.w};
#pragma unroll
      for (int j = 0; j < 16; j++) wsh[kg + j][mm] = wv[j];
    }
    __syncthreads();
    float a2[4] = {};
#pragma unroll 8
    for (int k = 0; k < 64; k++) {
      float4 a4 = *(const float4*)&wsh[k][ty * 4];
      float b = xsl[k][tx];
      a2[0] = fmaf(a4.x, b, a2[0]);
      a2[1] = fmaf(a4.y, b, a2[1]);
      a2[2] = fmaf(a4.z, b, a2[2]);
      a2[3] = fmaf(a4.w, b, a2[3]);
    }
#pragma unroll
    for (int im = 0; im < 4; im++) {
      int row = ch * 64 + ty * 4 + im;
      f1[row * NPIX + n0 + tx] = a2[im] + b1f[row];
    }
  }
}

// ---------------------------------------------------------------------------
// Depthwise 3x3 + exact GELU; 4 horizontal px/thread.
__global__ __launch_bounds__(256) void dw_gelu_kernel(
    const float* __restrict__ f1, const float* __restrict__ w,
    const float* __restrict__ b, float* __restrict__ f2) {
  int t = blockIdx.x * 256 + threadIdx.x;
  int c = t >> 10, pq = t & 1023;
  int py = pq >> 4, px0 = (pq & 15) << 2;
  const float* base = f1 + c * NPIX;
  float wv[9];
#pragma unroll
  for (int i = 0; i < 9; i++) wv[i] = w[c * 9 + i];
  float bc = b[c];
  float a[4] = {bc, bc, bc, bc};
#pragma unroll
  for (int dy = 0; dy < 3; dy++) {
    int y = py + dy - 1;
    if (y < 0 || y > 63) continue;
    const float* row = base + y * IMG + px0;
    float4 mid = *(const float4*)row;
    float left = (px0 > 0) ? row[-1] : 0.f;
    float right = (px0 < 60) ? row[4] : 0.f;
    float win[6] = {left, mid.x, mid.y, mid.z, mid.w, right};
#pragma unroll
    for (int o = 0; o < 4; o++)
#pragma unroll
      for (int dx = 0; dx < 3; dx++)
        a[o] = fmaf(wv[dy * 3 + dx], win[o + dx], a[o]);
  }
  float4 o4;
  float* op = &o4.x;
#pragma unroll
  for (int o = 0; o < 4; o++)
    op[o] = 0.5f * a[o] * (1.f + erff(a[o] * 0.70710678118654752f));
  *(float4*)&f2[c * NPIX + py * IMG + px0] = o4;
}

// ---------------------------------------------------------------------------
// ffn2 GEMM: out = W[64][256] * f2 + bias + x1 (residual). 16m x 64n tiles.
__global__ __launch_bounds__(256) void gemm16_kernel(
    const float* __restrict__ W, const float* __restrict__ X,
    const float* __restrict__ bias, const float* __restrict__ resid,
    float* __restrict__ C, int K) {
  __shared__ float xs[32][64];
  __shared__ float wsh[32][16];
  int n0 = blockIdx.x * 64, m0 = blockIdx.y * 16;
  int tid = threadIdx.x;
  int m = tid >> 4, ng = tid & 15;
  float acc[4] = {};
  for (int k0 = 0; k0 < K; k0 += 32) {
    {
      int i0 = tid * 2;
      int k = i0 >> 4, nf = (i0 & 15) * 4;
      *(float4*)&xs[k][nf] = *(const float4*)&X[(k0 + k) * NPIX + n0 + nf];
      int i1 = i0 + 1;
      int k1 = i1 >> 4, nf1 = (i1 & 15) * 4;
      *(float4*)&xs[k1][nf1] = *(const float4*)&X[(k0 + k1) * NPIX + n0 + nf1];
    }
#pragma unroll
    for (int e = tid; e < 512; e += 256) {
      int mm = e >> 5, kk = e & 31;
      wsh[kk][mm] = W[(m0 + mm) * K + k0 + kk];
    }
    __syncthreads();
#pragma unroll 8
    for (int kk = 0; kk < 32; kk++) {
      float a = wsh[kk][m];
      float4 b4 = *(const float4*)&xs[kk][ng * 4];
      acc[0] = fmaf(a, b4.x, acc[0]);
      acc[1] = fmaf(a, b4.y, acc[1]);
      acc[2] = fmaf(a, b4.z, acc[2]);
      acc[3] = fmaf(a, b4.w, acc[3]);
    }
    __syncthreads();
  }
  int row = m0 + m;
  float bv = bias[row];
  float4 o = make_float4(acc[0] + bv, acc[1] + bv, acc[2] + bv, acc[3] + bv);
  const float4 r4 = *(const float4*)&resid[row * NPIX + n0 + ng * 4];
  o.x += r4.x; o.y += r4.y; o.z += r4.z; o.w += r4.w;
  *(float4*)&C[row * NPIX + n0 + ng * 4] = o;
}

// ---------------------------------------------------------------------------
extern "C" void kernel_launch(void* const* d_in, const int* in_sizes, int n_in,
                              void* d_out, int out_size, void* d_ws,
                              size_t ws_size, hipStream_t stream) {
  const float* x      = (const float*)d_in[0];
  const float* luma   = (const float*)d_in[1];
  const float* ln1_w  = (const float*)d_in[2];
  const float* ln1_b  = (const float*)d_in[3];
  const float* qkv_w  = (const float*)d_in[4];
  const float* qkv_b  = (const float*)d_in[5];
  const float* proj_w = (const float*)d_in[6];
  const float* proj_b = (const float*)d_in[7];
  const float* lc1_w  = (const float*)d_in[8];
  const float* lc1_b  = (const float*)d_in[9];
  const float* lc2_w  = (const float*)d_in[10];
  const float* lc2_b  = (const float*)d_in[11];
  const float* gam_w  = (const float*)d_in[12];
  const float* gam_b  = (const float*)d_in[13];
  const float* bet_w  = (const float*)d_in[14];
  const float* bet_b  = (const float*)d_in[15];
  const float* alpha  = (const float*)d_in[16];
  const float* ln2_w  = (const float*)d_in[17];
  const float* ln2_b  = (const float*)d_in[18];
  const float* ffn1_w = (const float*)d_in[19];
  const float* ffn1_b = (const float*)d_in[20];
  const float* dw_w   = (const float*)d_in[21];
  const float* dw_b   = (const float*)d_in[22];
  const float* ffn2_w = (const float*)d_in[23];
  const float* ffn2_b = (const float*)d_in[24];
  float* out = (float*)d_out;

  float* w = (float*)d_ws;
  float* pooled = w + 0;        // 4096
  float* bsums  = w + 4096;     // 64 (16 used)
  unsigned short* cbuf = (unsigned short*)(w + 4160);     // 64 f (16 us used)
  unsigned short* qhl  = (unsigned short*)(w + 4224);     // 262144 f
  unsigned short* khl  = (unsigned short*)(w + 266368);   // 262144 f
  unsigned short* vthx = (unsigned short*)(w + 528512);   // 131072 f
  unsigned short* vtlx = (unsigned short*)(w + 659584);   // 131072 f
  float* pacc = w + 790656;    // 1048576
  float* pl   = w + 1839232;   // 131072
  float* x1   = w + 1970304;   // 262144
  float* f1   = w + 2232448;   // 1048576
  float* f2   = w + 3281024;   // 1048576
  float* h2   = w + 4329600;   // 131072

  lc_fused_kernel<<<dim3(16, 8), 256, 0, stream>>>(
      luma, lc1_w, lc1_b, lc2_w, lc2_b, h2, pooled, bsums, cbuf);
  ln_qkv_kernel<<<dim3(64, 3), 256, 0, stream>>>(
      x, ln1_w, ln1_b, qkv_w, qkv_b, gam_w, gam_b, bet_w, bet_b, h2, pooled,
      bsums, alpha, qhl, khl, vthx, vtlx);
  attn_kernel<<<dim3(64, 8, 4), 256, 0, stream>>>(qhl, khl, vthx, vtlx, cbuf,
                                                  pacc, pl);
  proj_ffn1_kernel<<<256, 256, 0, stream>>>(pacc, pl, proj_w, proj_b, x, ln2_w,
                                            ln2_b, ffn1_w, ffn1_b, x1, f1);
  dw_gelu_kernel<<<1024, 256, 0, stream>>>(f1, dw_w, dw_b, f2);
  gemm16_kernel<<<dim3(64, 4), 256, 0, stream>>>(ffn2_w, f2, ffn2_b, x1, out,
                                                 256);
}

// Round 7
// 219.178 us; speedup vs baseline: 1.3566x; 1.0979x over previous
//
#include <hip/hip_runtime.h>
#include <math.h>

// B=1, C=64, H=W=64, N=4096, heads=8, dh=8, inner=64, hid_lc=32, hid_f=256.
#define NPIX 4096
#define IMG 64

typedef __attribute__((ext_vector_type(8))) short bf16x8;
typedef __attribute__((ext_vector_type(4))) float floatx4;
typedef __attribute__((ext_vector_type(4))) unsigned int uintx4;

// fp32 -> (hi bf16 in low16) | (lo bf16 in high16), lo = x - f32(hi)
__device__ __forceinline__ unsigned int split_pack(float x) {
  unsigned int u = __float_as_uint(x);
  unsigned int hif = u & 0xffff0000u;
  float lof = x - __uint_as_float(hif);
  return (u >> 16) | (__float_as_uint(lof) & 0xffff0000u);
}

// pack hi16 of two floats: low16 = hi16(a), high16 = hi16(b)
__device__ __forceinline__ unsigned int hi_pair(float a, float b) {
  return (__float_as_uint(a) >> 16) | (__float_as_uint(b) & 0xffff0000u);
}

// ---------------------------------------------------------------------------
// Fused luma branch (unchanged from r6).
__global__ __launch_bounds__(256) void lc_fused_kernel(
    const float* __restrict__ luma, const float* __restrict__ w1,
    const float* __restrict__ b1, const float* __restrict__ w2,
    const float* __restrict__ b2, float* __restrict__ h2,
    float* __restrict__ pooled, float* __restrict__ bsums,
    unsigned short* __restrict__ cbuf) {
  __shared__ float tin[32][324];  // h1 on 18x18 halo per ic
  __shared__ float swt[4][32][9];
  __shared__ float red[256];
  int tile = blockIdx.x, ocg = blockIdx.y;
  int ty0 = (tile >> 2) * 16, tx0 = (tile & 3) * 16;
  int tid = threadIdx.x;
  if (tile == 0 && ocg == 0 && tid < 16) cbuf[tid] = (tid < 8) ? 0x3F80 : 0;
  for (int idx = tid; idx < 32 * 324; idx += 256) {
    int ic = idx / 324, pos = idx - ic * 324;
    int py = pos / 18, px = pos - py * 18;
    int gy = ty0 + py - 1, gx = tx0 + px - 1;
    float v = 0.f;
    if (gy >= 0 && gy < IMG && gx >= 0 && gx < IMG) {
      float s = b1[ic];
#pragma unroll
      for (int dy = 0; dy < 3; dy++)
#pragma unroll
        for (int dx = 0; dx < 3; dx++) {
          int y = gy + dy - 1, x = gx + dx - 1;
          if (y >= 0 && y < IMG && x >= 0 && x < IMG)
            s = fmaf(w1[ic * 9 + dy * 3 + dx], luma[y * IMG + x], s);
        }
      v = fmaxf(s, 0.f);
    }
    tin[ic][pos] = v;
  }
  for (int idx = tid; idx < 4 * 32 * 9; idx += 256) {
    int o = idx / 288, r = idx - o * 288;
    swt[o][r / 9][r % 9] = w2[(ocg * 4 + o) * 288 + r];
  }
  __syncthreads();
  int ly = tid >> 4, lx = tid & 15;
  int p = (ty0 + ly) * IMG + tx0 + lx;
  float acc[4];
#pragma unroll
  for (int o = 0; o < 4; o++) acc[o] = b2[ocg * 4 + o];
  for (int ic = 0; ic < 32; ic++) {
    float v[9];
#pragma unroll
    for (int dy = 0; dy < 3; dy++)
#pragma unroll
      for (int dx = 0; dx < 3; dx++)
        v[dy * 3 + dx] = tin[ic][(ly + dy) * 18 + lx + dx];
#pragma unroll
    for (int o = 0; o < 4; o++)
#pragma unroll
      for (int t = 0; t < 9; t++) acc[o] = fmaf(swt[o][ic][t], v[t], acc[o]);
  }
#pragma unroll
  for (int o = 0; o < 4; o++)
    h2[(ocg * 4 + o) * NPIX + p] = fmaxf(acc[o], 0.f);
  if (ocg == 0) {
    int gy = ty0 + ly, gx = tx0 + lx;
    float sv = 0.f;
#pragma unroll
    for (int dy = 0; dy < 3; dy++)
#pragma unroll
      for (int dx = 0; dx < 3; dx++) {
        int y = gy + dy - 1, x = gx + dx - 1;
        if (y >= 0 && y < IMG && x >= 0 && x < IMG) sv += luma[y * IMG + x];
      }
    float cy = 3.f - (gy == 0 ? 1.f : 0.f) - (gy == 63 ? 1.f : 0.f);
    float cx = 3.f - (gx == 0 ? 1.f : 0.f) - (gx == 63 ? 1.f : 0.f);
    float pv = (cy * cx - sv) * (1.f / 9.f);
    pooled[p] = pv;
    red[tid] = pv;
    __syncthreads();
    for (int st = 128; st > 0; st >>= 1) {
      if (tid < st) red[tid] += red[tid + st];
      __syncthreads();
    }
    if (tid == 0) bsums[tile] = red[0];
  }
}

// ---------------------------------------------------------------------------
// Fused per-pixel LayerNorm + qkv 1x1 GEMM + (gam/bet GEMMs in-register) +
// modulation + hi/lo split store (unchanged from r6). grid (64, 3).
__global__ __launch_bounds__(256) void ln_qkv_kernel(
    const float* __restrict__ X, const float* __restrict__ lnw,
    const float* __restrict__ lnb, const float* __restrict__ W,
    const float* __restrict__ bias, const float* __restrict__ gamW,
    const float* __restrict__ gamB, const float* __restrict__ betW,
    const float* __restrict__ betB, const float* __restrict__ h2,
    const float* __restrict__ pooled, const float* __restrict__ bsums,
    const float* __restrict__ alpha, unsigned short* __restrict__ qhl,
    unsigned short* __restrict__ khl, unsigned short* __restrict__ vthx,
    unsigned short* __restrict__ vtlx) {
  const float QSCALE = 0.35355339059327376f * 1.4426950408889634f;
  __shared__ float xs[64][64];
  __shared__ float wsh[64][64];
  __shared__ float h2s[32][64];
  __shared__ float wgs[32][64];
  __shared__ float wbs[32][64];
  __shared__ float psum[4][64];
  __shared__ float mu[64];
  __shared__ float rs[64];
  int n0 = blockIdx.x * 64, part = blockIdx.y, m0 = part * 64;
  int tid = threadIdx.x;
  int c = tid >> 2, pg = (tid & 3) * 16;
  {
    const float4* src = (const float4*)&X[c * NPIX + n0 + pg];
    float4* dst = (float4*)&xs[c][pg];
    dst[0] = src[0]; dst[1] = src[1]; dst[2] = src[2]; dst[3] = src[3];
  }
  {
    int m = tid >> 2, kg = (tid & 3) * 16;
    const float4* wr = (const float4*)&W[(m0 + m) * 64 + kg];
    float4 w0 = wr[0], w1 = wr[1], w2 = wr[2], w3 = wr[3];
    float wv[16] = {w0.x, w0.y, w0.z, w0.w, w1.x, w1.y, w1.z, w1.w,
                    w2.x, w2.y, w2.z, w2.w, w3.x, w3.y, w3.z, w3.w};
#pragma unroll
    for (int j = 0; j < 16; j++) wsh[kg + j][m] = wv[j];
  }
  {
    int i0 = tid * 2;
    int k = i0 >> 4, nf = (i0 & 15) * 4;
    *(float4*)&h2s[k][nf] = *(const float4*)&h2[k * NPIX + n0 + nf];
    int i1 = i0 + 1;
    int k1 = i1 >> 4, nf1 = (i1 & 15) * 4;
    *(float4*)&h2s[k1][nf1] = *(const float4*)&h2[k1 * NPIX + n0 + nf1];
  }
  {
    int m = tid >> 2, kg = (tid & 3) * 8;
    const float4* g0 = (const float4*)&gamW[m * 32 + kg];
    float4 a = g0[0], b4 = g0[1];
    float gv[8] = {a.x, a.y, a.z, a.w, b4.x, b4.y, b4.z, b4.w};
#pragma unroll
    for (int j = 0; j < 8; j++) wgs[kg + j][m] = gv[j];
    const float4* bb0 = (const float4*)&betW[m * 32 + kg];
    float4 c4 = bb0[0], d4 = bb0[1];
    float bv[8] = {c4.x, c4.y, c4.z, c4.w, d4.x, d4.y, d4.z, d4.w};
#pragma unroll
    for (int j = 0; j < 8; j++) wbs[kg + j][m] = bv[j];
  }
  __syncthreads();
  int px = tid & 63, qq = tid >> 6;
  float s = 0.f;
#pragma unroll
  for (int cc = 0; cc < 16; cc++) s += xs[qq * 16 + cc][px];
  psum[qq][px] = s;
  __syncthreads();
  if (tid < 64) {
    float t = psum[0][tid] + psum[1][tid] + psum[2][tid] + psum[3][tid];
    mu[tid] = t * (1.f / 64.f);
  }
  __syncthreads();
  float mm = mu[px];
  s = 0.f;
#pragma unroll
  for (int cc = 0; cc < 16; cc++) {
    float d = xs[qq * 16 + cc][px] - mm;
    s = fmaf(d, d, s);
  }
  psum[qq][px] = s;
  __syncthreads();
  if (tid < 64) {
    float t = psum[0][tid] + psum[1][tid] + psum[2][tid] + psum[3][tid];
    rs[tid] = rsqrtf(t * (1.f / 64.f) + 1e-5f);
  }
  __syncthreads();
  {
    float wc = lnw[c], bc = lnb[c];
#pragma unroll
    for (int j = 0; j < 16; j++) {
      int p = pg + j;
      xs[c][p] = (xs[c][p] - mu[p]) * rs[p] * wc + bc;
    }
  }
  __syncthreads();
  int tx = tid & 15, ty = tid >> 4;
  float ga[4][4] = {}, ba[4][4] = {};
#pragma unroll 8
  for (int kk = 0; kk < 32; kk++) {
    float4 wg4 = *(const float4*)&wgs[kk][ty * 4];
    float4 wb4 = *(const float4*)&wbs[kk][ty * 4];
    float4 h24 = *(const float4*)&h2s[kk][tx * 4];
    float gv[4] = {wg4.x, wg4.y, wg4.z, wg4.w};
    float bv[4] = {wb4.x, wb4.y, wb4.z, wb4.w};
    float hv[4] = {h24.x, h24.y, h24.z, h24.w};
#pragma unroll
    for (int im = 0; im < 4; im++)
#pragma unroll
      for (int in = 0; in < 4; in++) {
        ga[im][in] = fmaf(gv[im], hv[in], ga[im][in]);
        ba[im][in] = fmaf(bv[im], hv[in], ba[im][in]);
      }
  }
#pragma unroll
  for (int im = 0; im < 4; im++) {
    int cc = ty * 4 + im;
    float gb = gamB[cc], bb2 = betB[cc];
#pragma unroll
    for (int in = 0; in < 4; in++) {
      ga[im][in] += gb;
      ba[im][in] += bb2;
    }
  }
  float acc[4][4] = {};
#pragma unroll 8
  for (int kk = 0; kk < 64; kk++) {
    float4 a = *(const float4*)&wsh[kk][ty * 4];
    float4 b4 = *(const float4*)&xs[kk][tx * 4];
    float av[4] = {a.x, a.y, a.z, a.w};
    float bv[4] = {b4.x, b4.y, b4.z, b4.w};
#pragma unroll
    for (int im = 0; im < 4; im++)
#pragma unroll
      for (int in = 0; in < 4; in++)
        acc[im][in] = fmaf(av[im], bv[in], acc[im][in]);
  }
  float val[4][4];
#pragma unroll
  for (int im = 0; im < 4; im++) {
    int cc = ty * 4 + im;
    float bv = bias[m0 + cc];
#pragma unroll
    for (int in = 0; in < 4; in++)
      val[im][in] = fmaf(ga[im][in], acc[im][in] + bv, ba[im][in]);
  }
  if (part == 0) {
    float msum = 0.f;
#pragma unroll
    for (int t = 0; t < 16; t++) msum += bsums[t];
    float mean = msum * (1.f / 4096.f);
    float a0 = alpha[0];
    const float4 pv = *(const float4*)&pooled[n0 + tx * 4];
    float iv[4] = {a0 * (pv.x - mean), a0 * (pv.y - mean),
                   a0 * (pv.z - mean), a0 * (pv.w - mean)};
#pragma unroll
    for (int im = 0; im < 4; im++)
#pragma unroll
      for (int in = 0; in < 4; in++)
        val[im][in] = (val[im][in] + iv[in]) * QSCALE;
  }
  if (part < 2) {
    unsigned short* dst = (part == 0) ? qhl : khl;
    int h = ty >> 1, d0 = (ty & 1) * 4;
#pragma unroll
    for (int in = 0; in < 4; in++) {
      int n = n0 + tx * 4 + in;
      unsigned int pk[4];
#pragma unroll
      for (int im = 0; im < 4; im++) pk[im] = split_pack(val[im][in]);
      short4 hi, lo;
      hi.x = (short)(pk[0] & 0xffffu); hi.y = (short)(pk[1] & 0xffffu);
      hi.z = (short)(pk[2] & 0xffffu); hi.w = (short)(pk[3] & 0xffffu);
      lo.x = (short)(pk[0] >> 16); lo.y = (short)(pk[1] >> 16);
      lo.z = (short)(pk[2] >> 16); lo.w = (short)(pk[3] >> 16);
      unsigned short* base = dst + ((size_t)(h * NPIX + n) << 4) + d0;
      *(short4*)base = hi;
      *(short4*)(base + 8) = lo;
    }
  } else {
    int nq = n0 + tx * 4;
    int off0 = (nq >> 5) * 32 + ((nq >> 4) & 1) * 4 + ((nq >> 2) & 3) * 8;
#pragma unroll
    for (int im = 0; im < 4; im++) {
      int cc = ty * 4 + im;
      unsigned int pk[4];
#pragma unroll
      for (int in = 0; in < 4; in++) pk[in] = split_pack(val[im][in]);
      short4 hi, lo;
      hi.x = (short)(pk[0] & 0xffffu); hi.y = (short)(pk[1] & 0xffffu);
      hi.z = (short)(pk[2] & 0xffffu); hi.w = (short)(pk[3] & 0xffffu);
      lo.x = (short)(pk[0] >> 16); lo.y = (short)(pk[1] >> 16);
      lo.z = (short)(pk[2] >> 16); lo.w = (short)(pk[3] >> 16);
      *(short4*)(vthx + (size_t)cc * NPIX + off0) = hi;
      *(short4*)(vtlx + (size_t)cc * NPIX + off0) = lo;
    }
  }
}

// ---------------------------------------------------------------------------
// MFMA flash attention, S^T form, no online max, zero LDS. Each wave now owns
// TWO 16-query tiles off one k/v stream (halves L2 traffic). PV uses p_hi
// only (consistent with the ones-row denominator) + V-lo compensation.
// grid (32 i-tiles of 128, 8 heads, 4 jp).
__global__ __launch_bounds__(256, 4) void attn_kernel(
    const unsigned short* __restrict__ qhl,
    const unsigned short* __restrict__ khl,
    const unsigned short* __restrict__ vthx,
    const unsigned short* __restrict__ vtlx,
    const unsigned short* __restrict__ cbuf, float* __restrict__ pacc,
    float* __restrict__ pl) {
  int tid = threadIdx.x;
  int wave = tid >> 6, lane = tid & 63;
  int g = lane >> 4, c = lane & 15;
  int h = blockIdx.y, jp = blockIdx.z;
  int i0 = blockIdx.x * 128 + wave * 32;
  int jbase = jp * 1024;
  const bf16x8 qB0 = *(const bf16x8*)(qhl + ((size_t)(h * NPIX + i0 + c) << 4) +
                                      ((g & 1) << 3));
  const bf16x8 qB1 = *(const bf16x8*)(
      qhl + ((size_t)(h * NPIX + i0 + 16 + c) << 4) + ((g & 1) << 3));
  const unsigned short* kp =
      khl + ((size_t)(h * NPIX + jbase + c) << 4) + ((g >> 1) << 3);
  const unsigned short* vhp;
  const unsigned short* vlp;
  int vstep;
  if (c < 8) {
    vhp = vthx + (size_t)(h * 8 + c) * NPIX + jbase + (g << 3);
    vlp = vtlx + (size_t)(h * 8 + c) * NPIX + jbase + (g << 3);
    vstep = 32;
  } else {
    vhp = (c == 8) ? cbuf : (cbuf + 8);  // ones row / zero rows
    vlp = cbuf + 8;
    vstep = 0;
  }
  floatx4 zero4 = {0.f, 0.f, 0.f, 0.f};
  floatx4 aH0 = zero4, aM0 = zero4, aH1 = zero4, aM1 = zero4;
#pragma unroll 2
  for (int jt = 0; jt < 32; ++jt) {
    bf16x8 ka0 = *(const bf16x8*)kp;
    bf16x8 ka1 = *(const bf16x8*)(kp + 256);
    bf16x8 avh = *(const bf16x8*)vhp;
    bf16x8 avl = *(const bf16x8*)vlp;
    kp += 512;
    vhp += vstep;
    vlp += vstep;
    floatx4 s00 =
        __builtin_amdgcn_mfma_f32_16x16x32_bf16(ka0, qB0, zero4, 0, 0, 0);
    floatx4 s01 =
        __builtin_amdgcn_mfma_f32_16x16x32_bf16(ka1, qB0, zero4, 0, 0, 0);
    floatx4 s10 =
        __builtin_amdgcn_mfma_f32_16x16x32_bf16(ka0, qB1, zero4, 0, 0, 0);
    floatx4 s11 =
        __builtin_amdgcn_mfma_f32_16x16x32_bf16(ka1, qB1, zero4, 0, 0, 0);
    // tile 0
    {
      float p0 = __builtin_amdgcn_exp2f(fminf(s00[0], 80.f));
      float p1 = __builtin_amdgcn_exp2f(fminf(s00[1], 80.f));
      float p2 = __builtin_amdgcn_exp2f(fminf(s00[2], 80.f));
      float p3 = __builtin_amdgcn_exp2f(fminf(s00[3], 80.f));
      float p4 = __builtin_amdgcn_exp2f(fminf(s01[0], 80.f));
      float p5 = __builtin_amdgcn_exp2f(fminf(s01[1], 80.f));
      float p6 = __builtin_amdgcn_exp2f(fminf(s01[2], 80.f));
      float p7 = __builtin_amdgcn_exp2f(fminf(s01[3], 80.f));
      uintx4 bh;
      bh.x = hi_pair(p0, p1);
      bh.y = hi_pair(p2, p3);
      bh.z = hi_pair(p4, p5);
      bh.w = hi_pair(p6, p7);
      bf16x8 pbh = __builtin_bit_cast(bf16x8, bh);
      aH0 = __builtin_amdgcn_mfma_f32_16x16x32_bf16(avh, pbh, aH0, 0, 0, 0);
      aM0 = __builtin_amdgcn_mfma_f32_16x16x32_bf16(avl, pbh, aM0, 0, 0, 0);
    }
    // tile 1
    {
      float p0 = __builtin_amdgcn_exp2f(fminf(s10[0], 80.f));
      float p1 = __builtin_amdgcn_exp2f(fminf(s10[1], 80.f));
      float p2 = __builtin_amdgcn_exp2f(fminf(s10[2], 80.f));
      float p3 = __builtin_amdgcn_exp2f(fminf(s10[3], 80.f));
      float p4 = __builtin_amdgcn_exp2f(fminf(s11[0], 80.f));
      float p5 = __builtin_amdgcn_exp2f(fminf(s11[1], 80.f));
      float p6 = __builtin_amdgcn_exp2f(fminf(s11[2], 80.f));
      float p7 = __builtin_amdgcn_exp2f(fminf(s11[3], 80.f));
      uintx4 bh;
      bh.x = hi_pair(p0, p1);
      bh.y = hi_pair(p2, p3);
      bh.z = hi_pair(p4, p5);
      bh.w = hi_pair(p6, p7);
      bf16x8 pbh = __builtin_bit_cast(bf16x8, bh);
      aH1 = __builtin_amdgcn_mfma_f32_16x16x32_bf16(avh, pbh, aH1, 0, 0, 0);
      aM1 = __builtin_amdgcn_mfma_f32_16x16x32_bf16(avl, pbh, aM1, 0, 0, 0);
    }
  }
  floatx4 o0 = aH0 + aM0;
  floatx4 o1 = aH1 + aM1;
  if (g < 2) {
    size_t b0 = (size_t)((jp * 8 + h) * NPIX + i0 + c);
    *(float4*)&pacc[b0 * 8 + g * 4] = make_float4(o0[0], o0[1], o0[2], o0[3]);
    size_t b1 = b0 + 16;
    *(float4*)&pacc[b1 * 8 + g * 4] = make_float4(o1[0], o1[1], o1[2], o1[3]);
  } else if (g == 2) {
    pl[(size_t)((jp * 8 + h) * NPIX + i0 + c)] = o0[0];
    pl[(size_t)((jp * 8 + h) * NPIX + i0 + 16 + c)] = o1[0];
  }
}

// ---------------------------------------------------------------------------
// Fused: combine 4 j-partitions -> proj GEMM + bias + residual -> x1 (ch==0
// only) + LN2 stats -> LN apply -> one 64-ch slice of ffn1 -> f1.
// grid (128 n-tiles of 32, 4 ch-groups). Proj recomputed per ch-group.
__global__ __launch_bounds__(256) void proj_ffn1_kernel(
    const float* __restrict__ pacc, const float* __restrict__ pl,
    const float* __restrict__ Wp, const float* __restrict__ bp,
    const float* __restrict__ x, const float* __restrict__ ln2w,
    const float* __restrict__ ln2b, const float* __restrict__ W1,
    const float* __restrict__ b1f, float* __restrict__ x1,
    float* __restrict__ f1) {
  __shared__ float at[64][33];
  __shared__ float wsh[64][64];
  __shared__ float xsl[64][33];
  __shared__ float ps[8][33];
  __shared__ float pq[8][33];
  __shared__ float mus[32];
  __shared__ float rss[32];
  int n0 = blockIdx.x * 32;
  int ch = blockIdx.y;
  int tid = threadIdx.x;
  // stage proj weights [k][m]
  {
    int mm = tid >> 2, kg = (tid & 3) * 16;
    const float4* wr = (const float4*)&Wp[mm * 64 + kg];
    float4 w0 = wr[0], w1 = wr[1], w2 = wr[2], w3 = wr[3];
    float wv[16] = {w0.x, w0.y, w0.z, w0.w, w1.x, w1.y, w1.z, w1.w,
                    w2.x, w2.y, w2.z, w2.w, w3.x, w3.y, w3.z, w3.w};
#pragma unroll
    for (int j = 0; j < 16; j++) wsh[kg + j][mm] = wv[j];
  }
  // combine: one thread per (h, px)
  {
    int hh = tid >> 5, nn = tid & 31;
    int i = n0 + nn;
    float L = 0.f, o[8] = {};
#pragma unroll
    for (int p = 0; p < 4; p++) {
      size_t base = (size_t)((p * 8 + hh) * NPIX + i);
      L += pl[base];
      const float4 a0 = *(const float4*)&pacc[base * 8];
      const float4 a1 = *(const float4*)&pacc[base * 8 + 4];
      o[0] += a0.x; o[1] += a0.y; o[2] += a0.z; o[3] += a0.w;
      o[4] += a1.x; o[5] += a1.y; o[6] += a1.z; o[7] += a1.w;
    }
    float inv = 1.f / L;
#pragma unroll
    for (int d = 0; d < 8; d++) at[hh * 8 + d][nn] = o[d] * inv;
  }
  __syncthreads();
  int ty = tid >> 5, tx = tid & 31;  // 8 m-rows per thread, 1 px
  float acc[8] = {};
#pragma unroll 8
  for (int k = 0; k < 64; k++) {
    float b = at[k][tx];
    float4 a0 = *(const float4*)&wsh[k][ty * 8];
    float4 a1 = *(const float4*)&wsh[k][ty * 8 + 4];
    acc[0] = fmaf(a0.x, b, acc[0]);
    acc[1] = fmaf(a0.y, b, acc[1]);
    acc[2] = fmaf(a0.z, b, acc[2]);
    acc[3] = fmaf(a0.w, b, acc[3]);
    acc[4] = fmaf(a1.x, b, acc[4]);
    acc[5] = fmaf(a1.y, b, acc[5]);
    acc[6] = fmaf(a1.z, b, acc[6]);
    acc[7] = fmaf(a1.w, b, acc[7]);
  }
  float v[8], sn = 0.f, qn = 0.f;
#pragma unroll
  for (int im = 0; im < 8; im++) {
    int row = ty * 8 + im;
    float vv = acc[im] + bp[row] + x[row * NPIX + n0 + tx];
    v[im] = vv;
    sn += vv;
    qn = fmaf(vv, vv, qn);
  }
  if (ch == 0) {
#pragma unroll
    for (int im = 0; im < 8; im++)
      x1[(ty * 8 + im) * NPIX + n0 + tx] = v[im];
  }
  ps[ty][tx] = sn;
  pq[ty][tx] = qn;
  __syncthreads();
  if (tid < 32) {
    float s = 0.f, q = 0.f;
#pragma unroll
    for (int t = 0; t < 8; t++) {
      s += ps[t][tid];
      q += pq[t][tid];
    }
    float mu = s * (1.f / 64.f);
    mus[tid] = mu;
    rss[tid] = rsqrtf(q * (1.f / 64.f) - mu * mu + 1e-5f);
  }
  __syncthreads();
  {
    float muv = mus[tx], rsv = rss[tx];
#pragma unroll
    for (int im = 0; im < 8; im++) {
      int row = ty * 8 + im;
      xsl[row][tx] = (v[im] - muv) * rsv * ln2w[row] + ln2b[row];
    }
  }
  // restage wsh with this block's ffn1 weight slice (proj reads are done)
  {
    int mm = tid >> 2, kg = (tid & 3) * 16;
    const float4* wr = (const float4*)&W1[(ch * 64 + mm) * 64 + kg];
    float4 w0 = wr[0], w1 = wr[1], w2 = wr[2], w3 = wr[3];
    float wv[16] = {w0.x, w0.y, w0.z, w0.w, w1.x, w1.y, w1.z, w1.w,
                    w2.x, w2.y, w2.z, w2.w, w3.x, w3.y, w3.z, w3.w};
#pragma unroll
    for (int j = 0; j < 16; j++) wsh[kg + j][mm] = wv[j];
  }
  __syncthreads();
  float a2[8] = {};
#pragma unroll 8
  for (int k = 0; k < 64; k++) {
    float b = xsl[k][tx];
    float4 a0 = *(const float4*)&wsh[k][ty * 8];
    float4 a1 = *(const float4*)&wsh[k][ty * 8 + 4];
    a2[0] = fmaf(a0.x, b, a2[0]);
    a2[1] = fmaf(a0.y, b, a2[1]);
    a2[2] = fmaf(a0.z, b, a2[2]);
    a2[3] = fmaf(a0.w, b, a2[3]);
    a2[4] = fmaf(a1.x, b, a2[4]);
    a2[5] = fmaf(a1.y, b, a2[5]);
    a2[6] = fmaf(a1.z, b, a2[6]);
    a2[7] = fmaf(a1.w, b, a2[7]);
  }
#pragma unroll
  for (int im = 0; im < 8; im++) {
    int row = ch * 64 + ty * 8 + im;
    f1[row * NPIX + n0 + tx] = a2[im] + b1f[row];
  }
}

// ---------------------------------------------------------------------------
// Depthwise 3x3 + exact GELU; 4 horizontal px/thread (unchanged).
__global__ __launch_bounds__(256) void dw_gelu_kernel(
    const float* __restrict__ f1, const float* __restrict__ w,
    const float* __restrict__ b, float* __restrict__ f2) {
  int t = blockIdx.x * 256 + threadIdx.x;
  int c = t >> 10, pq = t & 1023;
  int py = pq >> 4, px0 = (pq & 15) << 2;
  const float* base = f1 + c * NPIX;
  float wv[9];
#pragma unroll
  for (int i = 0; i < 9; i++) wv[i] = w[c * 9 + i];
  float bc = b[c];
  float a[4] = {bc, bc, bc, bc};
#pragma unroll
  for (int dy = 0; dy < 3; dy++) {
    int y = py + dy - 1;
    if (y < 0 || y > 63) continue;
    const float* row = base + y * IMG + px0;
    float4 mid = *(const float4*)row;
    float left = (px0 > 0) ? row[-1] : 0.f;
    float right = (px0 < 60) ? row[4] : 0.f;
    float win[6] = {left, mid.x, mid.y, mid.z, mid.w, right};
#pragma unroll
    for (int o = 0; o < 4; o++)
#pragma unroll
      for (int dx = 0; dx < 3; dx++)
        a[o] = fmaf(wv[dy * 3 + dx], win[o + dx], a[o]);
  }
  float4 o4;
  float* op = &o4.x;
#pragma unroll
  for (int o = 0; o < 4; o++)
    op[o] = 0.5f * a[o] * (1.f + erff(a[o] * 0.70710678118654752f));
  *(float4*)&f2[c * NPIX + py * IMG + px0] = o4;
}

// ---------------------------------------------------------------------------
// ffn2 GEMM: out = W[64][256] * f2 + bias + x1 (residual). 16m x 64n tiles.
__global__ __launch_bounds__(256) void gemm16_kernel(
    const float* __restrict__ W, const float* __restrict__ X,
    const float* __restrict__ bias, const float* __restrict__ resid,
    float* __restrict__ C, int K) {
  __shared__ float xs[32][64];
  __shared__ float wsh[32][16];
  int n0 = blockIdx.x * 64, m0 = blockIdx.y * 16;
  int tid = threadIdx.x;
  int m = tid >> 4, ng = tid & 15;
  float acc[4] = {};
  for (int k0 = 0; k0 < K; k0 += 32) {
    {
      int i0 = tid * 2;
      int k = i0 >> 4, nf = (i0 & 15) * 4;
      *(float4*)&xs[k][nf] = *(const float4*)&X[(k0 + k) * NPIX + n0 + nf];
      int i1 = i0 + 1;
      int k1 = i1 >> 4, nf1 = (i1 & 15) * 4;
      *(float4*)&xs[k1][nf1] = *(const float4*)&X[(k0 + k1) * NPIX + n0 + nf1];
    }
#pragma unroll
    for (int e = tid; e < 512; e += 256) {
      int mm = e >> 5, kk = e & 31;
      wsh[kk][mm] = W[(m0 + mm) * K + k0 + kk];
    }
    __syncthreads();
#pragma unroll 8
    for (int kk = 0; kk < 32; kk++) {
      float a = wsh[kk][m];
      float4 b4 = *(const float4*)&xs[kk][ng * 4];
      acc[0] = fmaf(a, b4.x, acc[0]);
      acc[1] = fmaf(a, b4.y, acc[1]);
      acc[2] = fmaf(a, b4.z, acc[2]);
      acc[3] = fmaf(a, b4.w, acc[3]);
    }
    __syncthreads();
  }
  int row = m0 + m;
  float bv = bias[row];
  float4 o = make_float4(acc[0] + bv, acc[1] + bv, acc[2] + bv, acc[3] + bv);
  const float4 r4 = *(const float4*)&resid[row * NPIX + n0 + ng * 4];
  o.x += r4.x; o.y += r4.y; o.z += r4.z; o.w += r4.w;
  *(float4*)&C[row * NPIX + n0 + ng * 4] = o;
}

// ---------------------------------------------------------------------------
extern "C" void kernel_launch(void* const* d_in, const int* in_sizes, int n_in,
                              void* d_out, int out_size, void* d_ws,
                              size_t ws_size, hipStream_t stream) {
  const float* x      = (const float*)d_in[0];
  const float* luma   = (const float*)d_in[1];
  const float* ln1_w  = (const float*)d_in[2];
  const float* ln1_b  = (const float*)d_in[3];
  const float* qkv_w  = (const float*)d_in[4];
  const float* qkv_b  = (const float*)d_in[5];
  const float* proj_w = (const float*)d_in[6];
  const float* proj_b = (const float*)d_in[7];
  const float* lc1_w  = (const float*)d_in[8];
  const float* lc1_b  = (const float*)d_in[9];
  const float* lc2_w  = (const float*)d_in[10];
  const float* lc2_b  = (const float*)d_in[11];
  const float* gam_w  = (const float*)d_in[12];
  const float* gam_b  = (const float*)d_in[13];
  const float* bet_w  = (const float*)d_in[14];
  const float* bet_b  = (const float*)d_in[15];
  const float* alpha  = (const float*)d_in[16];
  const float* ln2_w  = (const float*)d_in[17];
  const float* ln2_b  = (const float*)d_in[18];
  const float* ffn1_w = (const float*)d_in[19];
  const float* ffn1_b = (const float*)d_in[20];
  const float* dw_w   = (const float*)d_in[21];
  const float* dw_b   = (const float*)d_in[22];
  const float* ffn2_w = (const float*)d_in[23];
  const float* ffn2_b = (const float*)d_in[24];
  float* out = (float*)d_out;

  float* w = (float*)d_ws;
  float* pooled = w + 0;        // 4096
  float* bsums  = w + 4096;     // 64 (16 used)
  unsigned short* cbuf = (unsigned short*)(w + 4160);     // 64 f (16 us used)
  unsigned short* qhl  = (unsigned short*)(w + 4224);     // 262144 f
  unsigned short* khl  = (unsigned short*)(w + 266368);   // 262144 f
  unsigned short* vthx = (unsigned short*)(w + 528512);   // 131072 f
  unsigned short* vtlx = (unsigned short*)(w + 659584);   // 131072 f
  float* pacc = w + 790656;    // 1048576
  float* pl   = w + 1839232;   // 131072
  float* x1   = w + 1970304;   // 262144
  float* f1   = w + 2232448;   // 1048576
  float* f2   = w + 3281024;   // 1048576
  float* h2   = w + 4329600;   // 131072

  lc_fused_kernel<<<dim3(16, 8), 256, 0, stream>>>(
      luma, lc1_w, lc1_b, lc2_w, lc2_b, h2, pooled, bsums, cbuf);
  ln_qkv_kernel<<<dim3(64, 3), 256, 0, stream>>>(
      x, ln1_w, ln1_b, qkv_w, qkv_b, gam_w, gam_b, bet_w, bet_b, h2, pooled,
      bsums, alpha, qhl, khl, vthx, vtlx);
  attn_kernel<<<dim3(32, 8, 4), 256, 0, stream>>>(qhl, khl, vthx, vtlx, cbuf,
                                                  pacc, pl);
  proj_ffn1_kernel<<<dim3(128, 4), 256, 0, stream>>>(
      pacc, pl, proj_w, proj_b, x, ln2_w, ln2_b, ffn1_w, ffn1_b, x1, f1);
  dw_gelu_kernel<<<1024, 256, 0, stream>>>(f1, dw_w, dw_b, f2);
  gemm16_kernel<<<dim3(64, 4), 256, 0, stream>>>(ffn2_w, f2, ffn2_b, x1, out,
                                                 256);
}

// Round 8
// 203.139 us; speedup vs baseline: 1.4637x; 1.0790x over previous
//
#include <hip/hip_runtime.h>
#include <math.h>

// B=1, C=64, H=W=64, N=4096, heads=8, dh=8, inner=64, hid_lc=32, hid_f=256.
#define NPIX 4096
#define IMG 64

typedef __attribute__((ext_vector_type(8))) short bf16x8;
typedef __attribute__((ext_vector_type(4))) float floatx4;
typedef __attribute__((ext_vector_type(4))) unsigned int uintx4;

// fp32 -> (hi bf16 in low16) | (lo bf16 in high16), lo = x - f32(hi)
__device__ __forceinline__ unsigned int split_pack(float x) {
  unsigned int u = __float_as_uint(x);
  unsigned int hif = u & 0xffff0000u;
  float lof = x - __uint_as_float(hif);
  return (u >> 16) | (__float_as_uint(lof) & 0xffff0000u);
}

// pack hi16 of two floats: low16 = hi16(a), high16 = hi16(b)
__device__ __forceinline__ unsigned int hi_pair(float a, float b) {
  return (__float_as_uint(a) >> 16) | (__float_as_uint(b) & 0xffff0000u);
}

// ---------------------------------------------------------------------------
// lc1: h1[32][4096] = relu(conv3x3(luma)), thread = 1 px x 4 oc.
// grid (16 px-tiles, 8 ocg). ocg==0 blocks also emit pooled + tile sums;
// block (0,0) initializes the attn constant buffer.
__global__ __launch_bounds__(256) void lc1_kernel(
    const float* __restrict__ luma, const float* __restrict__ w1,
    const float* __restrict__ b1, float* __restrict__ h1,
    float* __restrict__ pooled, float* __restrict__ bsums,
    unsigned short* __restrict__ cbuf) {
  __shared__ float red[256];
  int tile = blockIdx.x, ocg = blockIdx.y;
  int tid = threadIdx.x;
  if (tile == 0 && ocg == 0 && tid < 16) cbuf[tid] = (tid < 8) ? 0x3F80 : 0;
  int p = tile * 256 + tid;
  int py = p >> 6, px = p & 63;
  float v[9];
#pragma unroll
  for (int dy = 0; dy < 3; dy++)
#pragma unroll
    for (int dx = 0; dx < 3; dx++) {
      int y = py + dy - 1, x = px + dx - 1;
      v[dy * 3 + dx] =
          (y >= 0 && y < IMG && x >= 0 && x < IMG) ? luma[y * IMG + x] : 0.f;
    }
#pragma unroll
  for (int o = 0; o < 4; o++) {
    int oc = ocg * 4 + o;
    float s = b1[oc];
#pragma unroll
    for (int t = 0; t < 9; t++) s = fmaf(w1[oc * 9 + t], v[t], s);
    h1[oc * NPIX + p] = fmaxf(s, 0.f);
  }
  if (ocg == 0) {
    float sv = 0.f;
#pragma unroll
    for (int t = 0; t < 9; t++) sv += v[t];
    float cy = 3.f - (py == 0 ? 1.f : 0.f) - (py == 63 ? 1.f : 0.f);
    float cx = 3.f - (px == 0 ? 1.f : 0.f) - (px == 63 ? 1.f : 0.f);
    float pv = (cy * cx - sv) * (1.f / 9.f);
    pooled[p] = pv;
    red[tid] = pv;
    __syncthreads();
    for (int st = 128; st > 0; st >>= 1) {
      if (tid < st) red[tid] += red[tid + st];
      __syncthreads();
    }
    if (tid == 0) bsums[tile] = red[0];
  }
}

// ---------------------------------------------------------------------------
// lc2: h2[32][4096] = relu(conv3x3(h1)), halo staged FROM GLOBAL (1 load per
// position, not a conv recompute). grid (16 px-tiles of 16x16, 8 ocg of 4).
__global__ __launch_bounds__(256) void lc2_kernel(
    const float* __restrict__ h1, const float* __restrict__ w2,
    const float* __restrict__ b2, float* __restrict__ h2) {
  __shared__ float tin[32][324];  // 18x18 halo per ic
  __shared__ float swt[4][32][9];
  int tile = blockIdx.x, ocg = blockIdx.y;
  int ty0 = (tile >> 2) * 16, tx0 = (tile & 3) * 16;
  int tid = threadIdx.x;
  for (int idx = tid; idx < 32 * 324; idx += 256) {
    int ic = idx / 324, pos = idx - ic * 324;
    int py = pos / 18, px = pos - py * 18;
    int gy = ty0 + py - 1, gx = tx0 + px - 1;
    tin[ic][pos] = (gy >= 0 && gy < IMG && gx >= 0 && gx < IMG)
                       ? h1[ic * NPIX + gy * IMG + gx]
                       : 0.f;
  }
  for (int idx = tid; idx < 4 * 32 * 9; idx += 256) {
    int o = idx / 288, r = idx - o * 288;
    swt[o][r / 9][r % 9] = w2[(ocg * 4 + o) * 288 + r];
  }
  __syncthreads();
  int ly = tid >> 4, lx = tid & 15;
  int p = (ty0 + ly) * IMG + tx0 + lx;
  float acc[4];
#pragma unroll
  for (int o = 0; o < 4; o++) acc[o] = b2[ocg * 4 + o];
  for (int ic = 0; ic < 32; ic++) {
    float v[9];
#pragma unroll
    for (int dy = 0; dy < 3; dy++)
#pragma unroll
      for (int dx = 0; dx < 3; dx++)
        v[dy * 3 + dx] = tin[ic][(ly + dy) * 18 + lx + dx];
#pragma unroll
    for (int o = 0; o < 4; o++)
#pragma unroll
      for (int t = 0; t < 9; t++) acc[o] = fmaf(swt[o][ic][t], v[t], acc[o]);
  }
#pragma unroll
  for (int o = 0; o < 4; o++)
    h2[(ocg * 4 + o) * NPIX + p] = fmaxf(acc[o], 0.f);
}

// ---------------------------------------------------------------------------
// Fused per-pixel LayerNorm + qkv 1x1 GEMM + (gam/bet GEMMs in-register) +
// modulation + hi/lo split store (unchanged). grid (64, 3).
__global__ __launch_bounds__(256) void ln_qkv_kernel(
    const float* __restrict__ X, const float* __restrict__ lnw,
    const float* __restrict__ lnb, const float* __restrict__ W,
    const float* __restrict__ bias, const float* __restrict__ gamW,
    const float* __restrict__ gamB, const float* __restrict__ betW,
    const float* __restrict__ betB, const float* __restrict__ h2,
    const float* __restrict__ pooled, const float* __restrict__ bsums,
    const float* __restrict__ alpha, unsigned short* __restrict__ qhl,
    unsigned short* __restrict__ khl, unsigned short* __restrict__ vthx,
    unsigned short* __restrict__ vtlx) {
  const float QSCALE = 0.35355339059327376f * 1.4426950408889634f;
  __shared__ float xs[64][64];
  __shared__ float wsh[64][64];
  __shared__ float h2s[32][64];
  __shared__ float wgs[32][64];
  __shared__ float wbs[32][64];
  __shared__ float psum[4][64];
  __shared__ float mu[64];
  __shared__ float rs[64];
  int n0 = blockIdx.x * 64, part = blockIdx.y, m0 = part * 64;
  int tid = threadIdx.x;
  int c = tid >> 2, pg = (tid & 3) * 16;
  {
    const float4* src = (const float4*)&X[c * NPIX + n0 + pg];
    float4* dst = (float4*)&xs[c][pg];
    dst[0] = src[0]; dst[1] = src[1]; dst[2] = src[2]; dst[3] = src[3];
  }
  {
    int m = tid >> 2, kg = (tid & 3) * 16;
    const float4* wr = (const float4*)&W[(m0 + m) * 64 + kg];
    float4 w0 = wr[0], w1 = wr[1], w2 = wr[2], w3 = wr[3];
    float wv[16] = {w0.x, w0.y, w0.z, w0.w, w1.x, w1.y, w1.z, w1.w,
                    w2.x, w2.y, w2.z, w2.w, w3.x, w3.y, w3.z, w3.w};
#pragma unroll
    for (int j = 0; j < 16; j++) wsh[kg + j][m] = wv[j];
  }
  {
    int i0 = tid * 2;
    int k = i0 >> 4, nf = (i0 & 15) * 4;
    *(float4*)&h2s[k][nf] = *(const float4*)&h2[k * NPIX + n0 + nf];
    int i1 = i0 + 1;
    int k1 = i1 >> 4, nf1 = (i1 & 15) * 4;
    *(float4*)&h2s[k1][nf1] = *(const float4*)&h2[k1 * NPIX + n0 + nf1];
  }
  {
    int m = tid >> 2, kg = (tid & 3) * 8;
    const float4* g0 = (const float4*)&gamW[m * 32 + kg];
    float4 a = g0[0], b4 = g0[1];
    float gv[8] = {a.x, a.y, a.z, a.w, b4.x, b4.y, b4.z, b4.w};
#pragma unroll
    for (int j = 0; j < 8; j++) wgs[kg + j][m] = gv[j];
    const float4* bb0 = (const float4*)&betW[m * 32 + kg];
    float4 c4 = bb0[0], d4 = bb0[1];
    float bv[8] = {c4.x, c4.y, c4.z, c4.w, d4.x, d4.y, d4.z, d4.w};
#pragma unroll
    for (int j = 0; j < 8; j++) wbs[kg + j][m] = bv[j];
  }
  __syncthreads();
  int px = tid & 63, qq = tid >> 6;
  float s = 0.f;
#pragma unroll
  for (int cc = 0; cc < 16; cc++) s += xs[qq * 16 + cc][px];
  psum[qq][px] = s;
  __syncthreads();
  if (tid < 64) {
    float t = psum[0][tid] + psum[1][tid] + psum[2][tid] + psum[3][tid];
    mu[tid] = t * (1.f / 64.f);
  }
  __syncthreads();
  float mm = mu[px];
  s = 0.f;
#pragma unroll
  for (int cc = 0; cc < 16; cc++) {
    float d = xs[qq * 16 + cc][px] - mm;
    s = fmaf(d, d, s);
  }
  psum[qq][px] = s;
  __syncthreads();
  if (tid < 64) {
    float t = psum[0][tid] + psum[1][tid] + psum[2][tid] + psum[3][tid];
    rs[tid] = rsqrtf(t * (1.f / 64.f) + 1e-5f);
  }
  __syncthreads();
  {
    float wc = lnw[c], bc = lnb[c];
#pragma unroll
    for (int j = 0; j < 16; j++) {
      int p = pg + j;
      xs[c][p] = (xs[c][p] - mu[p]) * rs[p] * wc + bc;
    }
  }
  __syncthreads();
  int tx = tid & 15, ty = tid >> 4;
  float ga[4][4] = {}, ba[4][4] = {};
#pragma unroll 8
  for (int kk = 0; kk < 32; kk++) {
    float4 wg4 = *(const float4*)&wgs[kk][ty * 4];
    float4 wb4 = *(const float4*)&wbs[kk][ty * 4];
    float4 h24 = *(const float4*)&h2s[kk][tx * 4];
    float gv[4] = {wg4.x, wg4.y, wg4.z, wg4.w};
    float bv[4] = {wb4.x, wb4.y, wb4.z, wb4.w};
    float hv[4] = {h24.x, h24.y, h24.z, h24.w};
#pragma unroll
    for (int im = 0; im < 4; im++)
#pragma unroll
      for (int in = 0; in < 4; in++) {
        ga[im][in] = fmaf(gv[im], hv[in], ga[im][in]);
        ba[im][in] = fmaf(bv[im], hv[in], ba[im][in]);
      }
  }
#pragma unroll
  for (int im = 0; im < 4; im++) {
    int cc = ty * 4 + im;
    float gb = gamB[cc], bb2 = betB[cc];
#pragma unroll
    for (int in = 0; in < 4; in++) {
      ga[im][in] += gb;
      ba[im][in] += bb2;
    }
  }
  float acc[4][4] = {};
#pragma unroll 8
  for (int kk = 0; kk < 64; kk++) {
    float4 a = *(const float4*)&wsh[kk][ty * 4];
    float4 b4 = *(const float4*)&xs[kk][tx * 4];
    float av[4] = {a.x, a.y, a.z, a.w};
    float bv[4] = {b4.x, b4.y, b4.z, b4.w};
#pragma unroll
    for (int im = 0; im < 4; im++)
#pragma unroll
      for (int in = 0; in < 4; in++)
        acc[im][in] = fmaf(av[im], bv[in], acc[im][in]);
  }
  float val[4][4];
#pragma unroll
  for (int im = 0; im < 4; im++) {
    int cc = ty * 4 + im;
    float bv = bias[m0 + cc];
#pragma unroll
    for (int in = 0; in < 4; in++)
      val[im][in] = fmaf(ga[im][in], acc[im][in] + bv, ba[im][in]);
  }
  if (part == 0) {
    float msum = 0.f;
#pragma unroll
    for (int t = 0; t < 16; t++) msum += bsums[t];
    float mean = msum * (1.f / 4096.f);
    float a0 = alpha[0];
    const float4 pv = *(const float4*)&pooled[n0 + tx * 4];
    float iv[4] = {a0 * (pv.x - mean), a0 * (pv.y - mean),
                   a0 * (pv.z - mean), a0 * (pv.w - mean)};
#pragma unroll
    for (int im = 0; im < 4; im++)
#pragma unroll
      for (int in = 0; in < 4; in++)
        val[im][in] = (val[im][in] + iv[in]) * QSCALE;
  }
  if (part < 2) {
    unsigned short* dst = (part == 0) ? qhl : khl;
    int h = ty >> 1, d0 = (ty & 1) * 4;
#pragma unroll
    for (int in = 0; in < 4; in++) {
      int n = n0 + tx * 4 + in;
      unsigned int pk[4];
#pragma unroll
      for (int im = 0; im < 4; im++) pk[im] = split_pack(val[im][in]);
      short4 hi, lo;
      hi.x = (short)(pk[0] & 0xffffu); hi.y = (short)(pk[1] & 0xffffu);
      hi.z = (short)(pk[2] & 0xffffu); hi.w = (short)(pk[3] & 0xffffu);
      lo.x = (short)(pk[0] >> 16); lo.y = (short)(pk[1] >> 16);
      lo.z = (short)(pk[2] >> 16); lo.w = (short)(pk[3] >> 16);
      unsigned short* base = dst + ((size_t)(h * NPIX + n) << 4) + d0;
      *(short4*)base = hi;
      *(short4*)(base + 8) = lo;
    }
  } else {
    int nq = n0 + tx * 4;
    int off0 = (nq >> 5) * 32 + ((nq >> 4) & 1) * 4 + ((nq >> 2) & 3) * 8;
#pragma unroll
    for (int im = 0; im < 4; im++) {
      int cc = ty * 4 + im;
      unsigned int pk[4];
#pragma unroll
      for (int in = 0; in < 4; in++) pk[in] = split_pack(val[im][in]);
      short4 hi, lo;
      hi.x = (short)(pk[0] & 0xffffu); hi.y = (short)(pk[1] & 0xffffu);
      hi.z = (short)(pk[2] & 0xffffu); hi.w = (short)(pk[3] & 0xffffu);
      lo.x = (short)(pk[0] >> 16); lo.y = (short)(pk[1] >> 16);
      lo.z = (short)(pk[2] >> 16); lo.w = (short)(pk[3] >> 16);
      *(short4*)(vthx + (size_t)cc * NPIX + off0) = hi;
      *(short4*)(vtlx + (size_t)cc * NPIX + off0) = lo;
    }
  }
}

// ---------------------------------------------------------------------------
// MFMA flash attention (unchanged from r7). grid (32, 8, 4).
__global__ __launch_bounds__(256, 4) void attn_kernel(
    const unsigned short* __restrict__ qhl,
    const unsigned short* __restrict__ khl,
    const unsigned short* __restrict__ vthx,
    const unsigned short* __restrict__ vtlx,
    const unsigned short* __restrict__ cbuf, float* __restrict__ pacc,
    float* __restrict__ pl) {
  int tid = threadIdx.x;
  int wave = tid >> 6, lane = tid & 63;
  int g = lane >> 4, c = lane & 15;
  int h = blockIdx.y, jp = blockIdx.z;
  int i0 = blockIdx.x * 128 + wave * 32;
  int jbase = jp * 1024;
  const bf16x8 qB0 = *(const bf16x8*)(qhl + ((size_t)(h * NPIX + i0 + c) << 4) +
                                      ((g & 1) << 3));
  const bf16x8 qB1 = *(const bf16x8*)(
      qhl + ((size_t)(h * NPIX + i0 + 16 + c) << 4) + ((g & 1) << 3));
  const unsigned short* kp =
      khl + ((size_t)(h * NPIX + jbase + c) << 4) + ((g >> 1) << 3);
  const unsigned short* vhp;
  const unsigned short* vlp;
  int vstep;
  if (c < 8) {
    vhp = vthx + (size_t)(h * 8 + c) * NPIX + jbase + (g << 3);
    vlp = vtlx + (size_t)(h * 8 + c) * NPIX + jbase + (g << 3);
    vstep = 32;
  } else {
    vhp = (c == 8) ? cbuf : (cbuf + 8);  // ones row / zero rows
    vlp = cbuf + 8;
    vstep = 0;
  }
  floatx4 zero4 = {0.f, 0.f, 0.f, 0.f};
  floatx4 aH0 = zero4, aM0 = zero4, aH1 = zero4, aM1 = zero4;
#pragma unroll 2
  for (int jt = 0; jt < 32; ++jt) {
    bf16x8 ka0 = *(const bf16x8*)kp;
    bf16x8 ka1 = *(const bf16x8*)(kp + 256);
    bf16x8 avh = *(const bf16x8*)vhp;
    bf16x8 avl = *(const bf16x8*)vlp;
    kp += 512;
    vhp += vstep;
    vlp += vstep;
    floatx4 s00 =
        __builtin_amdgcn_mfma_f32_16x16x32_bf16(ka0, qB0, zero4, 0, 0, 0);
    floatx4 s01 =
        __builtin_amdgcn_mfma_f32_16x16x32_bf16(ka1, qB0, zero4, 0, 0, 0);
    floatx4 s10 =
        __builtin_amdgcn_mfma_f32_16x16x32_bf16(ka0, qB1, zero4, 0, 0, 0);
    floatx4 s11 =
        __builtin_amdgcn_mfma_f32_16x16x32_bf16(ka1, qB1, zero4, 0, 0, 0);
    {
      float p0 = __builtin_amdgcn_exp2f(fminf(s00[0], 80.f));
      float p1 = __builtin_amdgcn_exp2f(fminf(s00[1], 80.f));
      float p2 = __builtin_amdgcn_exp2f(fminf(s00[2], 80.f));
      float p3 = __builtin_amdgcn_exp2f(fminf(s00[3], 80.f));
      float p4 = __builtin_amdgcn_exp2f(fminf(s01[0], 80.f));
      float p5 = __builtin_amdgcn_exp2f(fminf(s01[1], 80.f));
      float p6 = __builtin_amdgcn_exp2f(fminf(s01[2], 80.f));
      float p7 = __builtin_amdgcn_exp2f(fminf(s01[3], 80.f));
      uintx4 bh;
      bh.x = hi_pair(p0, p1);
      bh.y = hi_pair(p2, p3);
      bh.z = hi_pair(p4, p5);
      bh.w = hi_pair(p6, p7);
      bf16x8 pbh = __builtin_bit_cast(bf16x8, bh);
      aH0 = __builtin_amdgcn_mfma_f32_16x16x32_bf16(avh, pbh, aH0, 0, 0, 0);
      aM0 = __builtin_amdgcn_mfma_f32_16x16x32_bf16(avl, pbh, aM0, 0, 0, 0);
    }
    {
      float p0 = __builtin_amdgcn_exp2f(fminf(s10[0], 80.f));
      float p1 = __builtin_amdgcn_exp2f(fminf(s10[1], 80.f));
      float p2 = __builtin_amdgcn_exp2f(fminf(s10[2], 80.f));
      float p3 = __builtin_amdgcn_exp2f(fminf(s10[3], 80.f));
      float p4 = __builtin_amdgcn_exp2f(fminf(s11[0], 80.f));
      float p5 = __builtin_amdgcn_exp2f(fminf(s11[1], 80.f));
      float p6 = __builtin_amdgcn_exp2f(fminf(s11[2], 80.f));
      float p7 = __builtin_amdgcn_exp2f(fminf(s11[3], 80.f));
      uintx4 bh;
      bh.x = hi_pair(p0, p1);
      bh.y = hi_pair(p2, p3);
      bh.z = hi_pair(p4, p5);
      bh.w = hi_pair(p6, p7);
      bf16x8 pbh = __builtin_bit_cast(bf16x8, bh);
      aH1 = __builtin_amdgcn_mfma_f32_16x16x32_bf16(avh, pbh, aH1, 0, 0, 0);
      aM1 = __builtin_amdgcn_mfma_f32_16x16x32_bf16(avl, pbh, aM1, 0, 0, 0);
    }
  }
  floatx4 o0 = aH0 + aM0;
  floatx4 o1 = aH1 + aM1;
  if (g < 2) {
    size_t b0 = (size_t)((jp * 8 + h) * NPIX + i0 + c);
    *(float4*)&pacc[b0 * 8 + g * 4] = make_float4(o0[0], o0[1], o0[2], o0[3]);
    size_t b1 = b0 + 16;
    *(float4*)&pacc[b1 * 8 + g * 4] = make_float4(o1[0], o1[1], o1[2], o1[3]);
  } else if (g == 2) {
    pl[(size_t)((jp * 8 + h) * NPIX + i0 + c)] = o0[0];
    pl[(size_t)((jp * 8 + h) * NPIX + i0 + 16 + c)] = o1[0];
  }
}

// ---------------------------------------------------------------------------
// Fused: combine -> proj GEMM + residual -> x1 (ch==0) + LN2 stats -> LN ->
// one 64-ch slice of ffn1 -> f1. grid (128, 4). (unchanged from r7)
__global__ __launch_bounds__(256) void proj_ffn1_kernel(
    const float* __restrict__ pacc, const float* __restrict__ pl,
    const float* __restrict__ Wp, const float* __restrict__ bp,
    const float* __restrict__ x, const float* __restrict__ ln2w,
    const float* __restrict__ ln2b, const float* __restrict__ W1,
    const float* __restrict__ b1f, float* __restrict__ x1,
    float* __restrict__ f1) {
  __shared__ float at[64][33];
  __shared__ float wsh[64][64];
  __shared__ float xsl[64][33];
  __shared__ float ps[8][33];
  __shared__ float pq[8][33];
  __shared__ float mus[32];
  __shared__ float rss[32];
  int n0 = blockIdx.x * 32;
  int ch = blockIdx.y;
  int tid = threadIdx.x;
  {
    int mm = tid >> 2, kg = (tid & 3) * 16;
    const float4* wr = (const float4*)&Wp[mm * 64 + kg];
    float4 w0 = wr[0], w1 = wr[1], w2 = wr[2], w3 = wr[3];
    float wv[16] = {w0.x, w0.y, w0.z, w0.w, w1.x, w1.y, w1.z, w1.w,
                    w2.x, w2.y, w2.z, w2.w, w3.x, w3.y, w3.z, w3.w};
#pragma unroll
    for (int j = 0; j < 16; j++) wsh[kg + j][mm] = wv[j];
  }
  {
    int hh = tid >> 5, nn = tid & 31;
    int i = n0 + nn;
    float L = 0.f, o[8] = {};
#pragma unroll
    for (int p = 0; p < 4; p++) {
      size_t base = (size_t)((p * 8 + hh) * NPIX + i);
      L += pl[base];
      const float4 a0 = *(const float4*)&pacc[base * 8];
      const float4 a1 = *(const float4*)&pacc[base * 8 + 4];
      o[0] += a0.x; o[1] += a0.y; o[2] += a0.z; o[3] += a0.w;
      o[4] += a1.x; o[5] += a1.y; o[6] += a1.z; o[7] += a1.w;
    }
    float inv = 1.f / L;
#pragma unroll
    for (int d = 0; d < 8; d++) at[hh * 8 + d][nn] = o[d] * inv;
  }
  __syncthreads();
  int ty = tid >> 5, tx = tid & 31;
  float acc[8] = {};
#pragma unroll 8
  for (int k = 0; k < 64; k++) {
    float b = at[k][tx];
    float4 a0 = *(const float4*)&wsh[k][ty * 8];
    float4 a1 = *(const float4*)&wsh[k][ty * 8 + 4];
    acc[0] = fmaf(a0.x, b, acc[0]);
    acc[1] = fmaf(a0.y, b, acc[1]);
    acc[2] = fmaf(a0.z, b, acc[2]);
    acc[3] = fmaf(a0.w, b, acc[3]);
    acc[4] = fmaf(a1.x, b, acc[4]);
    acc[5] = fmaf(a1.y, b, acc[5]);
    acc[6] = fmaf(a1.z, b, acc[6]);
    acc[7] = fmaf(a1.w, b, acc[7]);
  }
  float v[8], sn = 0.f, qn = 0.f;
#pragma unroll
  for (int im = 0; im < 8; im++) {
    int row = ty * 8 + im;
    float vv = acc[im] + bp[row] + x[row * NPIX + n0 + tx];
    v[im] = vv;
    sn += vv;
    qn = fmaf(vv, vv, qn);
  }
  if (ch == 0) {
#pragma unroll
    for (int im = 0; im < 8; im++)
      x1[(ty * 8 + im) * NPIX + n0 + tx] = v[im];
  }
  ps[ty][tx] = sn;
  pq[ty][tx] = qn;
  __syncthreads();
  if (tid < 32) {
    float s = 0.f, q = 0.f;
#pragma unroll
    for (int t = 0; t < 8; t++) {
      s += ps[t][tid];
      q += pq[t][tid];
    }
    float mu = s * (1.f / 64.f);
    mus[tid] = mu;
    rss[tid] = rsqrtf(q * (1.f / 64.f) - mu * mu + 1e-5f);
  }
  __syncthreads();
  {
    float muv = mus[tx], rsv = rss[tx];
#pragma unroll
    for (int im = 0; im < 8; im++) {
      int row = ty * 8 + im;
      xsl[row][tx] = (v[im] - muv) * rsv * ln2w[row] + ln2b[row];
    }
  }
  {
    int mm = tid >> 2, kg = (tid & 3) * 16;
    const float4* wr = (const float4*)&W1[(ch * 64 + mm) * 64 + kg];
    float4 w0 = wr[0], w1 = wr[1], w2 = wr[2], w3 = wr[3];
    float wv[16] = {w0.x, w0.y, w0.z, w0.w, w1.x, w1.y, w1.z, w1.w,
                    w2.x, w2.y, w2.z, w2.w, w3.x, w3.y, w3.z, w3.w};
#pragma unroll
    for (int j = 0; j < 16; j++) wsh[kg + j][mm] = wv[j];
  }
  __syncthreads();
  float a2[8] = {};
#pragma unroll 8
  for (int k = 0; k < 64; k++) {
    float b = xsl[k][tx];
    float4 a0 = *(const float4*)&wsh[k][ty * 8];
    float4 a1 = *(const float4*)&wsh[k][ty * 8 + 4];
    a2[0] = fmaf(a0.x, b, a2[0]);
    a2[1] = fmaf(a0.y, b, a2[1]);
    a2[2] = fmaf(a0.z, b, a2[2]);
    a2[3] = fmaf(a0.w, b, a2[3]);
    a2[4] = fmaf(a1.x, b, a2[4]);
    a2[5] = fmaf(a1.y, b, a2[5]);
    a2[6] = fmaf(a1.z, b, a2[6]);
    a2[7] = fmaf(a1.w, b, a2[7]);
  }
#pragma unroll
  for (int im = 0; im < 8; im++) {
    int row = ch * 64 + ty * 8 + im;
    f1[row * NPIX + n0 + tx] = a2[im] + b1f[row];
  }
}

// ---------------------------------------------------------------------------
// Depthwise 3x3 + exact GELU; 4 horizontal px/thread (unchanged).
__global__ __launch_bounds__(256) void dw_gelu_kernel(
    const float* __restrict__ f1, const float* __restrict__ w,
    const float* __restrict__ b, float* __restrict__ f2) {
  int t = blockIdx.x * 256 + threadIdx.x;
  int c = t >> 10, pq = t & 1023;
  int py = pq >> 4, px0 = (pq & 15) << 2;
  const float* base = f1 + c * NPIX;
  float wv[9];
#pragma unroll
  for (int i = 0; i < 9; i++) wv[i] = w[c * 9 + i];
  float bc = b[c];
  float a[4] = {bc, bc, bc, bc};
#pragma unroll
  for (int dy = 0; dy < 3; dy++) {
    int y = py + dy - 1;
    if (y < 0 || y > 63) continue;
    const float* row = base + y * IMG + px0;
    float4 mid = *(const float4*)row;
    float left = (px0 > 0) ? row[-1] : 0.f;
    float right = (px0 < 60) ? row[4] : 0.f;
    float win[6] = {left, mid.x, mid.y, mid.z, mid.w, right};
#pragma unroll
    for (int o = 0; o < 4; o++)
#pragma unroll
      for (int dx = 0; dx < 3; dx++)
        a[o] = fmaf(wv[dy * 3 + dx], win[o + dx], a[o]);
  }
  float4 o4;
  float* op = &o4.x;
#pragma unroll
  for (int o = 0; o < 4; o++)
    op[o] = 0.5f * a[o] * (1.f + erff(a[o] * 0.70710678118654752f));
  *(float4*)&f2[c * NPIX + py * IMG + px0] = o4;
}

// ---------------------------------------------------------------------------
// ffn2 GEMM: out = W[64][256] * f2 + bias + x1 (residual). (unchanged)
__global__ __launch_bounds__(256) void gemm16_kernel(
    const float* __restrict__ W, const float* __restrict__ X,
    const float* __restrict__ bias, const float* __restrict__ resid,
    float* __restrict__ C, int K) {
  __shared__ float xs[32][64];
  __shared__ float wsh[32][16];
  int n0 = blockIdx.x * 64, m0 = blockIdx.y * 16;
  int tid = threadIdx.x;
  int m = tid >> 4, ng = tid & 15;
  float acc[4] = {};
  for (int k0 = 0; k0 < K; k0 += 32) {
    {
      int i0 = tid * 2;
      int k = i0 >> 4, nf = (i0 & 15) * 4;
      *(float4*)&xs[k][nf] = *(const float4*)&X[(k0 + k) * NPIX + n0 + nf];
      int i1 = i0 + 1;
      int k1 = i1 >> 4, nf1 = (i1 & 15) * 4;
      *(float4*)&xs[k1][nf1] = *(const float4*)&X[(k0 + k1) * NPIX + n0 + nf1];
    }
#pragma unroll
    for (int e = tid; e < 512; e += 256) {
      int mm = e >> 5, kk = e & 31;
      wsh[kk][mm] = W[(m0 + mm) * K + k0 + kk];
    }
    __syncthreads();
#pragma unroll 8
    for (int kk = 0; kk < 32; kk++) {
      float a = wsh[kk][m];
      float4 b4 = *(const float4*)&xs[kk][ng * 4];
      acc[0] = fmaf(a, b4.x, acc[0]);
      acc[1] = fmaf(a, b4.y, acc[1]);
      acc[2] = fmaf(a, b4.z, acc[2]);
      acc[3] = fmaf(a, b4.w, acc[3]);
    }
    __syncthreads();
  }
  int row = m0 + m;
  float bv = bias[row];
  float4 o = make_float4(acc[0] + bv, acc[1] + bv, acc[2] + bv, acc[3] + bv);
  const float4 r4 = *(const float4*)&resid[row * NPIX + n0 + ng * 4];
  o.x += r4.x; o.y += r4.y; o.z += r4.z; o.w += r4.w;
  *(float4*)&C[row * NPIX + n0 + ng * 4] = o;
}

// ---------------------------------------------------------------------------
extern "C" void kernel_launch(void* const* d_in, const int* in_sizes, int n_in,
                              void* d_out, int out_size, void* d_ws,
                              size_t ws_size, hipStream_t stream) {
  const float* x      = (const float*)d_in[0];
  const float* luma   = (const float*)d_in[1];
  const float* ln1_w  = (const float*)d_in[2];
  const float* ln1_b  = (const float*)d_in[3];
  const float* qkv_w  = (const float*)d_in[4];
  const float* qkv_b  = (const float*)d_in[5];
  const float* proj_w = (const float*)d_in[6];
  const float* proj_b = (const float*)d_in[7];
  const float* lc1_w  = (const float*)d_in[8];
  const float* lc1_b  = (const float*)d_in[9];
  const float* lc2_w  = (const float*)d_in[10];
  const float* lc2_b  = (const float*)d_in[11];
  const float* gam_w  = (const float*)d_in[12];
  const float* gam_b  = (const float*)d_in[13];
  const float* bet_w  = (const float*)d_in[14];
  const float* bet_b  = (const float*)d_in[15];
  const float* alpha  = (const float*)d_in[16];
  const float* ln2_w  = (const float*)d_in[17];
  const float* ln2_b  = (const float*)d_in[18];
  const float* ffn1_w = (const float*)d_in[19];
  const float* ffn1_b = (const float*)d_in[20];
  const float* dw_w   = (const float*)d_in[21];
  const float* dw_b   = (const float*)d_in[22];
  const float* ffn2_w = (const float*)d_in[23];
  const float* ffn2_b = (const float*)d_in[24];
  float* out = (float*)d_out;

  float* w = (float*)d_ws;
  float* pooled = w + 0;        // 4096
  float* bsums  = w + 4096;     // 64 (16 used)
  unsigned short* cbuf = (unsigned short*)(w + 4160);     // 64 f (16 us used)
  unsigned short* qhl  = (unsigned short*)(w + 4224);     // 262144 f
  unsigned short* khl  = (unsigned short*)(w + 266368);   // 262144 f
  unsigned short* vthx = (unsigned short*)(w + 528512);   // 131072 f
  unsigned short* vtlx = (unsigned short*)(w + 659584);   // 131072 f
  float* pacc = w + 790656;    // 1048576
  float* pl   = w + 1839232;   // 131072
  float* x1   = w + 1970304;   // 262144
  float* f1   = w + 2232448;   // 1048576
  float* f2   = w + 3281024;   // 1048576
  float* h2   = w + 4329600;   // 131072
  float* h1   = w + 4460672;   // 131072

  lc1_kernel<<<dim3(16, 8), 256, 0, stream>>>(luma, lc1_w, lc1_b, h1, pooled,
                                              bsums, cbuf);
  lc2_kernel<<<dim3(16, 8), 256, 0, stream>>>(h1, lc2_w, lc2_b, h2);
  ln_qkv_kernel<<<dim3(64, 3), 256, 0, stream>>>(
      x, ln1_w, ln1_b, qkv_w, qkv_b, gam_w, gam_b, bet_w, bet_b, h2, pooled,
      bsums, alpha, qhl, khl, vthx, vtlx);
  attn_kernel<<<dim3(32, 8, 4), 256, 0, stream>>>(qhl, khl, vthx, vtlx, cbuf,
                                                  pacc, pl);
  proj_ffn1_kernel<<<dim3(128, 4), 256, 0, stream>>>(
      pacc, pl, proj_w, proj_b, x, ln2_w, ln2_b, ffn1_w, ffn1_b, x1, f1);
  dw_gelu_kernel<<<1024, 256, 0, stream>>>(f1, dw_w, dw_b, f2);
  gemm16_kernel<<<dim3(64, 4), 256, 0, stream>>>(ffn2_w, f2, ffn2_b, x1, out,
                                                 256);
}